// Round 10
// baseline (697.241 us; speedup 1.0000x reference)
//
#include <hip/hip_runtime.h>

typedef __bf16 bf16_t;
typedef __bf16 bf16x8 __attribute__((ext_vector_type(8)));
typedef __bf16 bf16x4 __attribute__((ext_vector_type(4)));
typedef float  f32x4  __attribute__((ext_vector_type(4)));
typedef int    i32x4  __attribute__((ext_vector_type(4)));

#define PL 136   // padded row stride (elems) for [t][128] bf16 tiles (272B = 16B-aligned)
#define PX 264   // padded row stride (elems) for [t][256] bf16 tiles

__device__ __forceinline__ f32x4 mfma16(bf16x8 a, bf16x8 b, f32x4 c) {
    return __builtin_amdgcn_mfma_f32_16x16x32_bf16(a, b, c, 0, 0, 0);
}

// barrier that drains LDS ops only — keeps global (vmcnt) loads in flight.
__device__ __forceinline__ void barrier_nodrain() {
    asm volatile("s_waitcnt lgkmcnt(0)" ::: "memory");
    __builtin_amdgcn_sched_barrier(0);
    __builtin_amdgcn_s_barrier();
    __builtin_amdgcn_sched_barrier(0);
}

// ---------------- merged prep: weight conversion + conditioning ----------------
__device__ __forceinline__ void conv8(const float* __restrict__ src,
                                      bf16_t* __restrict__ dst,
                                      int g, int M, int K) {
    int MK8 = (M * K) >> 3;
    int lay = g / MK8;
    int r = g - lay * MK8;
    int lane = r & 63, rest = r >> 6;
    int KB = K >> 5;
    int kb = rest % KB, mt = rest / KB;
    int m = mt * 16 + (lane & 15);
    int k = kb * 32 + ((lane >> 4) << 3);
    const float* s = src + (size_t)lay * M * K + (size_t)m * K + k;
    f32x4 v0 = *(const f32x4*)s;
    f32x4 v1 = *(const f32x4*)(s + 4);
    bf16x8 o;
    o[0] = (bf16_t)v0[0]; o[1] = (bf16_t)v0[1]; o[2] = (bf16_t)v0[2]; o[3] = (bf16_t)v0[3];
    o[4] = (bf16_t)v1[0]; o[5] = (bf16_t)v1[1]; o[6] = (bf16_t)v1[2]; o[7] = (bf16_t)v1[3];
    *(bf16x8*)(dst + (size_t)g * 8) = o;
}

__global__ __launch_bounds__(256) void k_prep(
                       const float* __restrict__ rw, const float* __restrict__ kw,
                       const float* __restrict__ s1w, const float* __restrict__ s2w,
                       const float* __restrict__ e1w, const float* __restrict__ dwt,
                       const float* __restrict__ cond_w, const float* __restrict__ end2_w,
                       const float* __restrict__ end2_b, const float* __restrict__ en,
                       bf16_t* __restrict__ Ares, bf16_t* __restrict__ Askp,
                       bf16_t* __restrict__ A1, bf16_t* __restrict__ A2,
                       bf16_t* __restrict__ Ae, bf16_t* __restrict__ Adil,
                       float* __restrict__ cond_all, float* __restrict__ cond2) {
    if (blockIdx.x >= 1744) {
        __shared__ f32x4 en_s[1024];
        __shared__ f32x4 red[1024];
        int bi = blockIdx.x - 1744;
        int i = bi >> 4;            // 0..30
        int n = (bi >> 2) & 3;
        int og = bi & 3;
        int tid = threadIdx.x;
        const f32x4* ep = (const f32x4*)(en + (size_t)n * 4096);
        for (int idx = tid; idx < 1024; idx += 256) en_s[idx] = ep[idx];
        __syncthreads();
        int o_loc = tid >> 2, part = tid & 3;
        int o = og * 64 + o_loc;
        const float* W = (i < 30) ? cond_w + ((size_t)i * 256 + o) * 256
                                  : end2_w + (size_t)o * 256;
        const float* Wp = W + part * 64;
        f32x4 a0 = {0.f,0.f,0.f,0.f}, a1 = a0, a2 = a0, a3 = a0;
        for (int c = 0; c < 64; c += 4) {
            f32x4 wv = *(const f32x4*)(Wp + c);
            int cg2 = part * 64 + c;
            #pragma unroll
            for (int cc = 0; cc < 4; ++cc) {
                float wf = wv[cc];
                a0 += wf * en_s[(cg2 + cc) * 4 + 0];
                a1 += wf * en_s[(cg2 + cc) * 4 + 1];
                a2 += wf * en_s[(cg2 + cc) * 4 + 2];
                a3 += wf * en_s[(cg2 + cc) * 4 + 3];
            }
        }
        red[tid * 4 + 0] = a0; red[tid * 4 + 1] = a1;
        red[tid * 4 + 2] = a2; red[tid * 4 + 3] = a3;
        __syncthreads();
        if (tid < 64) {
            int o2 = og * 64 + tid;
            float bias = (i < 30) ? 0.f : end2_b[o2];
            float* dst = (i < 30) ? cond_all + (((size_t)i * 4 + n) * 256 + o2) * 16
                                  : cond2 + ((size_t)n * 256 + o2) * 16;
            f32x4* d4 = (f32x4*)dst;
            #pragma unroll
            for (int t = 0; t < 4; ++t) {
                f32x4 s = red[(tid * 4 + 0) * 4 + t] + red[(tid * 4 + 1) * 4 + t]
                        + red[(tid * 4 + 2) * 4 + t] + red[(tid * 4 + 3) * 4 + t];
                d4[t] = s + bias;
            }
        }
        return;
    }
    int g = blockIdx.x * 256 + threadIdx.x;
    if (g < 61440) { conv8(rw, Ares, g, 128, 128); return; }
    g -= 61440;
    if (g < 122880) { conv8(kw, Askp, g, 256, 128); return; }
    g -= 122880;
    if (g < 4096) { conv8(s1w, A1, g, 128, 256); return; }
    g -= 4096;
    if (g < 4096) { conv8(s2w, A2, g, 256, 128); return; }
    g -= 4096;
    if (g < 8192) { conv8(e1w, Ae, g, 256, 256); return; }
    g -= 8192;
    {   // dil_w -> per-layer A[256][256], 8 elems/thread (64B span, stride-2 pick)
        int lay = g >> 13, r = g & 8191;
        int lane = r & 63, rest = r >> 6;
        int kb = rest & 7, mt = rest >> 3;
        int m = mt * 16 + (lane & 15);
        int k0 = kb * 32 + ((lane >> 4) << 3);
        int sel = (k0 < 128) ? 0 : 1;
        int kk = (k0 < 128) ? k0 : k0 - 128;
        const float* s = dwt + (((size_t)lay * 256 + m) * 128 + kk) * 2;
        f32x4 c0 = *(const f32x4*)(s);
        f32x4 c1 = *(const f32x4*)(s + 4);
        f32x4 c2 = *(const f32x4*)(s + 8);
        f32x4 c3 = *(const f32x4*)(s + 12);
        bf16x8 o;
        o[0] = (bf16_t)c0[sel];     o[1] = (bf16_t)c0[2 + sel];
        o[2] = (bf16_t)c1[sel];     o[3] = (bf16_t)c1[2 + sel];
        o[4] = (bf16_t)c2[sel];     o[5] = (bf16_t)c2[2 + sel];
        o[6] = (bf16_t)c3[sel];     o[7] = (bf16_t)c3[2 + sel];
        *(bf16x8*)(Adil + (size_t)lay * 65536 + (size_t)r * 8) = o;
    }
}

// ---------------- start: l0 = start1@x ; s0 = start2@l0 (t>=4096) ----------------
__global__ __launch_bounds__(512, 4) void k_start(
    const float* __restrict__ x, bf16_t* __restrict__ la, float* __restrict__ sbuf,
    const bf16_t* __restrict__ A1, const bf16_t* __restrict__ A2, int t_base)
{
    __shared__ __align__(16) bf16_t xt[64 * PX];
    __shared__ __align__(16) bf16_t l0[64 * PL];
    int tid = threadIdx.x;
    int n = blockIdx.y, t0 = t_base + blockIdx.x * 64;
    int lane = tid & 63, w = tid >> 6, i16 = lane & 15, q = lane >> 4;
    f32x4 z = {0.f,0.f,0.f,0.f};
    {
        int t = tid & 63;
        for (int c = tid >> 6; c < 256; c += 8)
            xt[t * PX + c] = (bf16_t)x[((size_t)n * 256 + c) * 8192 + t0 + t];
    }
    __syncthreads();
    f32x4 acc[4] = {z,z,z,z};
    #pragma unroll
    for (int kb = 0; kb < 8; ++kb) {
        int koff = kb * 32 + q * 8;
        bf16x8 bf[4];
        #pragma unroll
        for (int nt = 0; nt < 4; ++nt)
            bf[nt] = *(const bf16x8*)(xt + (nt * 16 + i16) * PX + koff);
        bf16x8 af = *(const bf16x8*)(A1 + (((size_t)w * 8 + kb) * 64 + lane) * 8);
        #pragma unroll
        for (int nt = 0; nt < 4; ++nt) acc[nt] = mfma16(af, bf[nt], acc[nt]);
    }
    #pragma unroll
    for (int nt = 0; nt < 4; ++nt)
        #pragma unroll
        for (int j = 0; j < 4; ++j)
            l0[(nt * 16 + i16) * PL + w * 16 + q * 4 + j] = (bf16_t)acc[nt][j];
    __syncthreads();
    {
        int r = tid >> 4, col = (tid & 15) * 8;
        #pragma unroll
        for (int p = 0; p < 2; ++p) {
            int rr = r + p * 32;
            *(i32x4*)(la + ((size_t)n * 8192 + t0 + rr) * 128 + col) =
                *(const i32x4*)(l0 + rr * PL + col);
        }
    }
    if (t0 >= 4096) {
        f32x4 a2[2][4] = {{z,z,z,z},{z,z,z,z}};
        #pragma unroll
        for (int kb = 0; kb < 4; ++kb) {
            int koff = kb * 32 + q * 8;
            bf16x8 bf[4];
            #pragma unroll
            for (int nt = 0; nt < 4; ++nt)
                bf[nt] = *(const bf16x8*)(l0 + (nt * 16 + i16) * PL + koff);
            #pragma unroll
            for (int mt2 = 0; mt2 < 2; ++mt2) {
                bf16x8 af = *(const bf16x8*)(A2 + ((((size_t)2 * w + mt2) * 4 + kb) * 64 + lane) * 8);
                #pragma unroll
                for (int nt = 0; nt < 4; ++nt) a2[mt2][nt] = mfma16(af, bf[nt], a2[mt2][nt]);
            }
        }
        float* sp = sbuf + (size_t)n * 256 * 4096 + (t0 - 4096);
        #pragma unroll
        for (int mt2 = 0; mt2 < 2; ++mt2)
            #pragma unroll
            for (int nt = 0; nt < 4; ++nt)
                #pragma unroll
                for (int j = 0; j < 4; ++j) {
                    int o = (2 * w + mt2) * 16 + q * 4 + j;
                    sp[(size_t)o * 4096 + nt * 16 + i16] = a2[mt2][nt][j];
                }
    }
}

// ---------------- fused 6 small-dil layers (dil 1..32), halo-recompute ----------
// Tile: 64 owned rows + 64 halo = 128-row SINGLE buffer, updated IN PLACE with a
// BACKWARD chunk sweep (chunk r0 reads rows [r0-d, r0+32) — still layer k-1 data:
// own rows pre-write, lower rows written only by later (lower) chunks). sm2 is
// ping-ponged so each chunk needs ONE barrier. 52 KB LDS -> 2 blocks/CU.
// Row r <-> t = t0 - 64 + r. Halo rows garbage-but-contained (clamped del reads).
template<int USEG>
__global__ __launch_bounds__(512, 4) void k_fuse(
    const bf16_t* __restrict__ l_in, bf16_t* __restrict__ l_out,
    bf16_t* __restrict__ G,
    const bf16_t* __restrict__ Adil, const bf16_t* __restrict__ Ares,
    const float* __restrict__ condA, int aG, int g0)
{
    __shared__ __align__(16) bf16_t buf[128 * PL];
    __shared__ __align__(16) bf16_t sm2[2][32 * PL];
    int tid = threadIdx.x;
    int n = blockIdx.y, t0 = aG + blockIdx.x * 64;
    int lane = tid & 63, w = tid >> 6, i16 = lane & 15, q = lane >> 4;
    f32x4 z = {0.f,0.f,0.f,0.f};
    int c_base = w * 16 + q * 4;
    size_t base = (size_t)n * 8192;
    // stage rows [t0-64, t0+64) -> buf (128 rows; t<0 -> zeros, causal pad)
    {
        int rr0 = tid >> 4, col = (tid & 15) * 8;
        for (int rr = rr0; rr < 128; rr += 32) {
            int t = t0 - 64 + rr;
            i32x4 v = {0, 0, 0, 0};
            if (t >= 0) v = *(const i32x4*)(l_in + (base + t) * 128 + col);
            *(i32x4*)(buf + rr * PL + col) = v;
        }
    }
    barrier_nodrain();
    int p = 0;
    #pragma unroll 1
    for (int k = 0; k < 6; ++k) {
        int i = g0 + k;
        int d = 1 << k;
        const bf16x8* AdF = (const bf16x8*)(Adil + (size_t)i * 65536);
        const bf16x8* ArF = (const bf16x8*)(Ares + (size_t)i * 16384);
        const float* cond = condA + ((size_t)i * 4 + n) * 4096;
        bf16_t* Gl = G + (size_t)i * (4ull * 4096 * 128);
        float cv_s[4], cv_t[4];
        #pragma unroll
        for (int j = 0; j < 4; ++j) {
            cv_s[j] = cond[(c_base + j) * 16 + i16];
            cv_t[j] = cond[(c_base + j + 128) * 16 + i16];
        }
        bf16x8 a_s[8], a_t[8];
        #pragma unroll
        for (int kb = 0; kb < 8; ++kb) {
            a_s[kb] = AdF[((size_t)w * 8 + kb) * 64 + lane];
            a_t[kb] = AdF[((size_t)(w + 8) * 8 + kb) * 64 + lane];
        }
        bf16x8 ar[4];
        #pragma unroll
        for (int kb = 0; kb < 4; ++kb)
            ar[kb] = ArF[((size_t)w * 4 + kb) * 64 + lane];
        // BACKWARD sweep: r0 = 96, 64, 32, 0 (in-place safe)
        #pragma unroll 1
        for (int r0 = 96; r0 >= 0; r0 -= 32) {
            // GEMM1: d-tile = [W_del W_cur] @ [l(r-d); l(r)], M=256 K=256 N=32
            f32x4 accs[2] = {z,z}, acct[2] = {z,z};
            #pragma unroll
            for (int kb = 0; kb < 8; ++kb) {
                int koff = (kb & 3) * 32 + q * 8;
                bf16x8 bf[2];
                #pragma unroll
                for (int nt = 0; nt < 2; ++nt) {
                    int rr = r0 + nt * 16 + i16;
                    int dr = (kb < 4) ? (rr - d) : rr;
                    if (dr < 0) dr = 0;   // clamped: garbage stays in invalid rows
                    bf[nt] = *(const bf16x8*)(buf + dr * PL + koff);
                }
                #pragma unroll
                for (int nt = 0; nt < 2; ++nt) {
                    accs[nt] = mfma16(a_s[kb], bf[nt], accs[nt]);
                    acct[nt] = mfma16(a_t[kb], bf[nt], acct[nt]);
                }
            }
            // gate -> sm2[p]
            bf16_t* s2 = sm2[p];
            #pragma unroll
            for (int nt = 0; nt < 2; ++nt) {
                bf16x4 g4;
                #pragma unroll
                for (int j = 0; j < 4; ++j) {
                    float vlo = accs[nt][j] + cv_s[j];
                    float vhi = acct[nt][j] + cv_t[j];
                    float sg = 1.0f / (1.0f + __expf(-vlo));
                    float th = 1.0f - 2.0f / (1.0f + __expf(2.0f * vhi));
                    g4[j] = (bf16_t)(sg * th);
                }
                *(bf16x4*)(s2 + (nt * 16 + i16) * PL + c_base) = g4;
            }
            barrier_nodrain();   // GEMM1 reads + gate writes drained; ONE barrier/chunk
            int t_chunk = t0 + (r0 - 64);
            if (USEG && r0 >= 64 && t_chunk >= 4096) {
                // gate tile -> G in fragment order (16B/thread, coalesced)
                int tt = ((tid & 256) >> 4) + (tid & 15);
                int cc = ((tid >> 6) & 3) * 32 + ((tid >> 4) & 3) * 8;
                bf16x8 gv = *(const bf16x8*)(s2 + tt * PL + cc);
                *(bf16x8*)(Gl + ((size_t)n * 4096 + (t_chunk - 4096)) * 128 + tid * 8) = gv;
            }
            // res GEMM + residual add -> buf rows [r0, r0+32) IN PLACE
            f32x4 acc2[2] = {z,z};
            #pragma unroll
            for (int kb = 0; kb < 4; ++kb) {
                int koff = kb * 32 + q * 8;
                #pragma unroll
                for (int nt = 0; nt < 2; ++nt) {
                    bf16x8 bf = *(const bf16x8*)(s2 + (nt * 16 + i16) * PL + koff);
                    acc2[nt] = mfma16(ar[kb], bf, acc2[nt]);
                }
            }
            #pragma unroll
            for (int nt = 0; nt < 2; ++nt) {
                int rr = r0 + nt * 16 + i16;
                bf16x4 lv = *(const bf16x4*)(buf + rr * PL + c_base);
                bf16x4 o4;
                #pragma unroll
                for (int j = 0; j < 4; ++j)
                    o4[j] = (bf16_t)((float)lv[j] + acc2[nt][j]);
                *(bf16x4*)(buf + rr * PL + c_base) = o4;
            }
            p ^= 1;
        }
    }
    barrier_nodrain();
    // final: rows [64,128) of buf -> l_out [t0, t0+64)
    {
        int rr0 = tid >> 4, col = (tid & 15) * 8;
        for (int rr = 64 + rr0; rr < 128; rr += 32) {
            *(i32x4*)(l_out + (base + t0 - 64 + rr) * 128 + col) =
                *(const i32x4*)(buf + rr * PL + col);
        }
    }
}

// ---------------- single layer, TT=32 (r3-proven; used for dil>=64) ----------------
template<int USEG>
__global__ __launch_bounds__(512, 4) void k_layer(
    const bf16_t* __restrict__ l_in, bf16_t* __restrict__ l_out,
    float* __restrict__ sbuf, bf16_t* __restrict__ Gl,
    const bf16_t* __restrict__ Ad, const bf16_t* __restrict__ Ar,
    const bf16_t* __restrict__ Ak, const float* __restrict__ condL,
    int dil, int t_base, int do_res)
{
    __shared__ __align__(16) bf16_t smA[64 * PL];   // staging (cur|del or combined)
    __shared__ __align__(16) bf16_t sm2[32 * PL];   // gate
    int tid = threadIdx.x;
    int n = blockIdx.y, t0 = t_base + blockIdx.x * 32;
    int lane = tid & 63, w = tid >> 6, i16 = lane & 15, q = lane >> 4;
    f32x4 z = {0.f,0.f,0.f,0.f};
    const float* cond = condL + (size_t)n * 4096;
    int r = tid >> 4, col = (tid & 15) * 8;
    int c_base = w * 16 + q * 4;
    size_t base = (size_t)n * 8192;

    float cv_s[4], cv_t[4];
    #pragma unroll
    for (int j = 0; j < 4; ++j) {
        cv_s[j] = cond[(c_base + j) * 16 + i16];
        cv_t[j] = cond[(c_base + j + 128) * 16 + i16];
    }
    const bf16x8* AdF = (const bf16x8*)Ad;
    bf16x8 a_s[8], a_t[8];
    #pragma unroll
    for (int kb = 0; kb < 8; ++kb) {
        a_s[kb] = AdF[((size_t)w * 8 + kb) * 64 + lane];
        a_t[kb] = AdF[((size_t)(w + 8) * 8 + kb) * 64 + lane];
    }

    const bf16_t* curp;
    const bf16_t* delp;
    if (dil < 32) {
        int cnt = (32 + dil) * 16;
        for (int idx = tid; idx < cnt; idx += 512) {
            int rr = idx >> 4, c2 = (idx & 15) * 8;
            *(i32x4*)(smA + rr * PL + c2) =
                *(const i32x4*)(l_in + (base + t0 - dil + rr) * 128 + c2);
        }
        delp = smA; curp = smA + dil * PL;
    } else {
        *(i32x4*)(smA + r * PL + col) =
            *(const i32x4*)(l_in + (base + t0 + r) * 128 + col);
        int gp = t0 - dil + r;
        i32x4 v = {0, 0, 0, 0};
        if (gp >= 0) v = *(const i32x4*)(l_in + (base + gp) * 128 + col);
        *(i32x4*)(smA + (32 + r) * PL + col) = v;
        curp = smA; delp = smA + 32 * PL;
    }
    barrier_nodrain();

    f32x4 accs[2] = {z,z}, acct[2] = {z,z};
    #pragma unroll
    for (int kb = 0; kb < 8; ++kb) {
        const bf16_t* bsrc = (kb < 4) ? delp : curp;
        int koff = (kb & 3) * 32 + q * 8;
        bf16x8 bf[2];
        #pragma unroll
        for (int nt = 0; nt < 2; ++nt)
            bf[nt] = *(const bf16x8*)(bsrc + (nt * 16 + i16) * PL + koff);
        #pragma unroll
        for (int nt = 0; nt < 2; ++nt) {
            accs[nt] = mfma16(a_s[kb], bf[nt], accs[nt]);
            acct[nt] = mfma16(a_t[kb], bf[nt], acct[nt]);
        }
    }

    const bf16x8* ArF = (const bf16x8*)Ar;
    bf16x8 ar[4];
    if (do_res) {
        #pragma unroll
        for (int kb = 0; kb < 4; ++kb)
            ar[kb] = ArF[((size_t)w * 4 + kb) * 64 + lane];
    }

    {
        #pragma unroll
        for (int nt = 0; nt < 2; ++nt) {
            bf16x4 g4;
            #pragma unroll
            for (int j = 0; j < 4; ++j) {
                float vlo = accs[nt][j] + cv_s[j];
                float vhi = acct[nt][j] + cv_t[j];
                float sg = 1.0f / (1.0f + __expf(-vlo));
                float th = 1.0f - 2.0f / (1.0f + __expf(2.0f * vhi));
                g4[j] = (bf16_t)(sg * th);
            }
            *(bf16x4*)(sm2 + (nt * 16 + i16) * PL + c_base) = g4;
        }
    }
    barrier_nodrain();

    if (USEG) {
        if (t0 >= 4096) {
            int tt = ((tid & 256) >> 4) + (tid & 15);
            int cc = ((tid >> 6) & 3) * 32 + ((tid >> 4) & 3) * 8;
            bf16x8 gv = *(const bf16x8*)(sm2 + tt * PL + cc);
            *(bf16x8*)(Gl + ((size_t)n * 4096 + (t0 - 4096)) * 128 + tid * 8) = gv;
        }
    }

    f32x4 acc2[2] = {z,z};
    if (do_res || !USEG) {
        int do_skip = (!USEG) && (t0 >= 4096);
        f32x4 acc3[2][2] = {{z,z},{z,z}};
        const bf16x8* AkF = (const bf16x8*)Ak;
        #pragma unroll
        for (int kb = 0; kb < 4; ++kb) {
            int koff = kb * 32 + q * 8;
            bf16x8 bf[2];
            #pragma unroll
            for (int nt = 0; nt < 2; ++nt)
                bf[nt] = *(const bf16x8*)(sm2 + (nt * 16 + i16) * PL + koff);
            if (do_res) {
                #pragma unroll
                for (int nt = 0; nt < 2; ++nt) acc2[nt] = mfma16(ar[kb], bf[nt], acc2[nt]);
            }
            if (do_skip) {
                #pragma unroll
                for (int mt2 = 0; mt2 < 2; ++mt2) {
                    bf16x8 ak = AkF[((size_t)(2 * w + mt2) * 4 + kb) * 64 + lane];
                    #pragma unroll
                    for (int nt = 0; nt < 2; ++nt)
                        acc3[mt2][nt] = mfma16(ak, bf[nt], acc3[mt2][nt]);
                }
            }
        }
        if (do_skip) {
            float* sp = sbuf + (size_t)n * 256 * 4096 + (t0 - 4096);
            #pragma unroll
            for (int mt2 = 0; mt2 < 2; ++mt2)
                #pragma unroll
                for (int nt = 0; nt < 2; ++nt)
                    #pragma unroll
                    for (int j = 0; j < 4; ++j) {
                        int o = (2 * w + mt2) * 16 + q * 4 + j;
                        sp[(size_t)o * 4096 + nt * 16 + i16] += acc3[mt2][nt][j];
                    }
        }
    }

    if (do_res) {
        #pragma unroll
        for (int nt = 0; nt < 2; ++nt) {
            int trow = (nt * 16 + i16) * PL;
            bf16x4 lv = *(const bf16x4*)(curp + trow + c_base);
            bf16x4 o4;
            #pragma unroll
            for (int j = 0; j < 4; ++j)
                o4[j] = (bf16_t)((float)lv[j] + acc2[nt][j]);
            *(bf16x4*)(l_out + (base + t0 + nt * 16 + i16) * 128 + c_base) = o4;
        }
    }
}

// ---------------- deferred skip mega-GEMM: s += sum_i skip_i @ g_i ----------------
#define SKIP_HALF(I, AKU, AKP, GW0, GW1)                                        \
    {                                                                           \
        const int i_ = (I);                                                     \
        if (i_ + 1 < 30) {                                                      \
            bf16_t* db = gbuf[(i_ + 1) & 1];                                    \
            *(i32x4*)(db + tid * 8) = GW0;                                      \
            *(i32x4*)(db + 4096 + tid * 8) = GW1;                               \
        }                                                                       \
        if (i_ + 3 < 30) {                                                      \
            const bf16_t* srcp = gb + (size_t)(i_ + 3) * GLS;                   \
            GW0 = *(const i32x4*)(srcp);                                        \
            GW1 = *(const i32x4*)(srcp + 4096);                                 \
        }                                                                       \
        if (i_ + 1 < 30) {                                                      \
            const bf16x8* An = (const bf16x8*)(Askp + (size_t)(i_ + 1) * 32768);\
            _Pragma("unroll")                                                   \
            for (int kb = 0; kb < 4; ++kb) {                                    \
                AKP[2 * kb]     = An[fi0 + kb * 64];                            \
                AKP[2 * kb + 1] = An[fi1 + kb * 64];                            \
            }                                                                   \
        }                                                                       \
        const bf16_t* gp_ = gbuf[i_ & 1];                                       \
        _Pragma("unroll")                                                       \
        for (int kb = 0; kb < 4; ++kb) {                                        \
            _Pragma("unroll")                                                   \
            for (int nt = 0; nt < 4; ++nt) {                                    \
                bf16x8 bfv = *(const bf16x8*)(gp_ + (nt >> 1) * 4096 +          \
                              (((nt & 1) * 4 + kb) * 64 + lane) * 8);           \
                acc[0][nt] = mfma16(AKU[2 * kb], bfv, acc[0][nt]);              \
                acc[1][nt] = mfma16(AKU[2 * kb + 1], bfv, acc[1][nt]);          \
            }                                                                   \
        }                                                                       \
        if (i_ + 1 < 30) {                                                      \
            asm volatile("s_waitcnt lgkmcnt(0)" ::: "memory");                  \
            __builtin_amdgcn_sched_barrier(0);                                  \
            __builtin_amdgcn_s_barrier();                                       \
            __builtin_amdgcn_sched_barrier(0);                                  \
        }                                                                       \
    }

__global__ __launch_bounds__(512, 2) void k_skip(
    const bf16_t* __restrict__ G, float* __restrict__ sbuf,
    const bf16_t* __restrict__ Askp)
{
    __shared__ __align__(16) bf16_t gbuf[2][8192];
    int tid = threadIdx.x;
    int n = blockIdx.y, t0 = blockIdx.x * 64;
    int lane = tid & 63, w = tid >> 6, i16 = lane & 15, q = lane >> 4;
    f32x4 z = {0.f,0.f,0.f,0.f};
    f32x4 acc[2][4] = {{z,z,z,z},{z,z,z,z}};
    const size_t GLS = (size_t)4 * 4096 * 128;   // per-layer stride in G (elems)
    const bf16_t* gb = G + ((size_t)n * 4096 + t0) * 128 + tid * 8;
    int fi0 = (2 * w) * 256 + lane;
    int fi1 = fi0 + 256;
    bf16x8 akA[8], akB[8];
    {
        const bf16x8* A0 = (const bf16x8*)Askp;
        #pragma unroll
        for (int kb = 0; kb < 4; ++kb) {
            akA[2 * kb]     = A0[fi0 + kb * 64];
            akA[2 * kb + 1] = A0[fi1 + kb * 64];
        }
    }
    i32x4 gA0, gA1, gB0, gB1;
    {
        i32x4 t0v = *(const i32x4*)(gb);
        i32x4 t1v = *(const i32x4*)(gb + 4096);
        *(i32x4*)(gbuf[0] + tid * 8) = t0v;
        *(i32x4*)(gbuf[0] + 4096 + tid * 8) = t1v;
    }
    gA0 = *(const i32x4*)(gb + 1 * GLS);
    gA1 = *(const i32x4*)(gb + 1 * GLS + 4096);
    gB0 = *(const i32x4*)(gb + 2 * GLS);
    gB1 = *(const i32x4*)(gb + 2 * GLS + 4096);
    __syncthreads();   // prologue: single full drain
    #pragma unroll 1
    for (int ii = 0; ii < 30; ii += 2) {
        SKIP_HALF(ii,     akA, akB, gA0, gA1)
        SKIP_HALF(ii + 1, akB, akA, gB0, gB1)
    }
    float* sp = sbuf + (size_t)n * 256 * 4096 + t0;
    #pragma unroll
    for (int mt2 = 0; mt2 < 2; ++mt2)
        #pragma unroll
        for (int nt = 0; nt < 4; ++nt)
            #pragma unroll
            for (int j = 0; j < 4; ++j) {
                int o = (2 * w + mt2) * 16 + q * 4 + j;
                sp[(size_t)o * 4096 + nt * 16 + i16] += acc[mt2][nt][j];
            }
}

// ---------------- end: out = relu(end1@relu(s) + b1 + cond2_tiled) ----------------
__global__ __launch_bounds__(512) void k_end(
    const float* __restrict__ sbuf, float* __restrict__ out,
    const bf16_t* __restrict__ Ae, const float* __restrict__ cond2,
    const float* __restrict__ b1)
{
    __shared__ __align__(16) bf16_t st[64 * PX];
    __shared__ float c2[4096];
    __shared__ float b1s[256];
    int tid = threadIdx.x;
    int n = blockIdx.y, t0 = blockIdx.x * 64;
    int lane = tid & 63, w = tid >> 6, i16 = lane & 15, q = lane >> 4;
    f32x4 z = {0.f,0.f,0.f,0.f};
    {
        int t = tid & 63;
        for (int c = tid >> 6; c < 256; c += 8) {
            float v = sbuf[((size_t)n * 256 + c) * 4096 + t0 + t];
            st[t * PX + c] = (bf16_t)fmaxf(v, 0.f);
        }
        const f32x4* cc = (const f32x4*)(cond2 + (size_t)n * 4096);
        for (int idx = tid; idx < 1024; idx += 512) ((f32x4*)c2)[idx] = cc[idx];
        if (tid < 64) ((f32x4*)b1s)[tid] = ((const f32x4*)b1)[tid];
    }
    __syncthreads();
    f32x4 acc[2][4] = {{z,z,z,z},{z,z,z,z}};
    #pragma unroll
    for (int kb = 0; kb < 8; ++kb) {
        int koff = kb * 32 + q * 8;
        bf16x8 bf[4];
        #pragma unroll
        for (int nt = 0; nt < 4; ++nt)
            bf[nt] = *(const bf16x8*)(st + (nt * 16 + i16) * PX + koff);
        #pragma unroll
        for (int mt2 = 0; mt2 < 2; ++mt2) {
            bf16x8 af = *(const bf16x8*)(Ae + ((((size_t)2 * w + mt2) * 8 + kb) * 64 + lane) * 8);
            #pragma unroll
            for (int nt = 0; nt < 4; ++nt) acc[mt2][nt] = mfma16(af, bf[nt], acc[mt2][nt]);
        }
    }
    #pragma unroll
    for (int mt2 = 0; mt2 < 2; ++mt2)
        #pragma unroll
        for (int j = 0; j < 4; ++j) {
            int o = (2 * w + mt2) * 16 + q * 4 + j;
            float bb = b1s[o] + c2[o * 16 + i16];
            #pragma unroll
            for (int nt = 0; nt < 4; ++nt) {
                float v = acc[mt2][nt][j] + bb;
                out[((size_t)n * 256 + o) * 4096 + t0 + nt * 16 + i16] = fmaxf(v, 0.f);
            }
        }
}

extern "C" void kernel_launch(void* const* d_in, const int* in_sizes, int n_in,
                              void* d_out, int out_size, void* d_ws, size_t ws_size,
                              hipStream_t stream) {
    const float* x   = (const float*)d_in[0];
    const float* en  = (const float*)d_in[1];
    const float* s1w = (const float*)d_in[2];
    const float* s2w = (const float*)d_in[3];
    const float* cw  = (const float*)d_in[4];
    const float* dw  = (const float*)d_in[5];
    const float* rw  = (const float*)d_in[6];
    const float* kw  = (const float*)d_in[7];
    const float* e1w = (const float*)d_in[8];
    const float* e1b = (const float*)d_in[9];
    const float* e2w = (const float*)d_in[10];
    const float* e2b = (const float*)d_in[11];
    float* out = (float*)d_out;

    char* p = (char*)d_ws;
    auto take = [&](size_t bytes) {
        char* r = p;
        p += (bytes + 255) & ~(size_t)255;
        return r;
    };
    bf16_t* A1   = (bf16_t*)take((size_t)128 * 256 * 2);
    bf16_t* A2   = (bf16_t*)take((size_t)256 * 128 * 2);
    bf16_t* Ae   = (bf16_t*)take((size_t)256 * 256 * 2);
    bf16_t* Adil = (bf16_t*)take((size_t)30 * 65536 * 2);
    bf16_t* Ares = (bf16_t*)take((size_t)30 * 16384 * 2);
    bf16_t* Askp = (bf16_t*)take((size_t)30 * 32768 * 2);
    float*  condA= (float*)take((size_t)30 * 16384 * 4);
    float*  cond2= (float*)take((size_t)16384 * 4);
    bf16_t* la   = (bf16_t*)take((size_t)4 * 8192 * 128 * 2);
    bf16_t* lb   = (bf16_t*)take((size_t)4 * 8192 * 128 * 2);
    float*  sbuf = (float*)take((size_t)4 * 256 * 4096 * 4);
    bf16_t* G    = (bf16_t*)take((size_t)30 * 4 * 4096 * 128 * 2);  // last
    bool useG = ((size_t)(p - (char*)d_ws) <= ws_size);

    k_prep<<<2240, 256, 0, stream>>>(rw, kw, s1w, s2w, e1w, dw,
                                     cw, e2w, e2b, en,
                                     Ares, Askp, A1, A2, Ae, Adil, condA, cond2);

    // causal trim table (host)
    int a[30];
    a[29] = 4096;
    for (int i = 28; i >= 0; --i) {
        int nx = a[i + 1] - (1 << ((i + 1) % 10));
        a[i] = nx < 4096 ? (nx & ~63) : 4096;
    }

    k_start<<<dim3(127, 4), 512, 0, stream>>>(x, la, sbuf, A1, A2, 64);

    bf16_t* src = la;
    bf16_t* dst = lb;
    if (useG) {
        for (int g = 0; g < 3; ++g) {
            int g0 = g * 10;
            int aG = a[g0] & ~63;
            dim3 gridF((8192 - aG) / 64, 4);
            k_fuse<1><<<gridF, 512, 0, stream>>>(src, dst, G, Adil, Ares,
                                                 condA, aG, g0);
            { bf16_t* t = src; src = dst; dst = t; }
            for (int i = g0 + 6; i < g0 + 10; ++i) {
                dim3 grid2((8192 - a[i]) / 32, 4);
                k_layer<1><<<grid2, 512, 0, stream>>>(src, dst, sbuf,
                    G + (size_t)i * 4 * 4096 * 128,
                    Adil + (size_t)i * 65536, Ares + (size_t)i * 16384,
                    Askp + (size_t)i * 32768, condA + (size_t)i * 16384,
                    1 << (i % 10), a[i], i < 29 ? 1 : 0);
                bf16_t* t = src; src = dst; dst = t;
            }
        }
        k_skip<<<dim3(64, 4), 512, 0, stream>>>(G, sbuf, Askp);
    } else {
        for (int i = 0; i < 30; ++i) {
            dim3 grid((8192 - a[i]) / 32, 4);
            k_layer<0><<<grid, 512, 0, stream>>>(src, dst, sbuf, (bf16_t*)nullptr,
                Adil + (size_t)i * 65536, Ares + (size_t)i * 16384,
                Askp + (size_t)i * 32768, condA + (size_t)i * 16384,
                1 << (i % 10), a[i], i < 29 ? 1 : 0);
            bf16_t* t = src; src = dst; dst = t;
        }
    }
    k_end<<<dim3(64, 4), 512, 0, stream>>>(sbuf, out, Ae, cond2, e1b);
}

// Round 11
// 628.109 us; speedup vs baseline: 1.1101x; 1.1101x over previous
//
#include <hip/hip_runtime.h>

typedef __bf16 bf16_t;
typedef __bf16 bf16x8 __attribute__((ext_vector_type(8)));
typedef __bf16 bf16x4 __attribute__((ext_vector_type(4)));
typedef float  f32x4  __attribute__((ext_vector_type(4)));
typedef int    i32x4  __attribute__((ext_vector_type(4)));

#define PL 136   // padded row stride (elems) for [t][128] bf16 tiles (272B = 16B-aligned)
#define PX 264   // padded row stride (elems) for [t][256] bf16 tiles

__device__ __forceinline__ f32x4 mfma16(bf16x8 a, bf16x8 b, f32x4 c) {
    return __builtin_amdgcn_mfma_f32_16x16x32_bf16(a, b, c, 0, 0, 0);
}

// barrier that drains LDS ops only — keeps global (vmcnt) loads in flight.
__device__ __forceinline__ void barrier_nodrain() {
    asm volatile("s_waitcnt lgkmcnt(0)" ::: "memory");
    __builtin_amdgcn_sched_barrier(0);
    __builtin_amdgcn_s_barrier();
    __builtin_amdgcn_sched_barrier(0);
}

// ---------------- merged prep: weight conversion + conditioning ----------------
__device__ __forceinline__ void conv8(const float* __restrict__ src,
                                      bf16_t* __restrict__ dst,
                                      int g, int M, int K) {
    int MK8 = (M * K) >> 3;
    int lay = g / MK8;
    int r = g - lay * MK8;
    int lane = r & 63, rest = r >> 6;
    int KB = K >> 5;
    int kb = rest % KB, mt = rest / KB;
    int m = mt * 16 + (lane & 15);
    int k = kb * 32 + ((lane >> 4) << 3);
    const float* s = src + (size_t)lay * M * K + (size_t)m * K + k;
    f32x4 v0 = *(const f32x4*)s;
    f32x4 v1 = *(const f32x4*)(s + 4);
    bf16x8 o;
    o[0] = (bf16_t)v0[0]; o[1] = (bf16_t)v0[1]; o[2] = (bf16_t)v0[2]; o[3] = (bf16_t)v0[3];
    o[4] = (bf16_t)v1[0]; o[5] = (bf16_t)v1[1]; o[6] = (bf16_t)v1[2]; o[7] = (bf16_t)v1[3];
    *(bf16x8*)(dst + (size_t)g * 8) = o;
}

__global__ __launch_bounds__(256) void k_prep(
                       const float* __restrict__ rw, const float* __restrict__ kw,
                       const float* __restrict__ s1w, const float* __restrict__ s2w,
                       const float* __restrict__ e1w, const float* __restrict__ dwt,
                       const float* __restrict__ cond_w, const float* __restrict__ end2_w,
                       const float* __restrict__ end2_b, const float* __restrict__ en,
                       bf16_t* __restrict__ Ares, bf16_t* __restrict__ Askp,
                       bf16_t* __restrict__ A1, bf16_t* __restrict__ A2,
                       bf16_t* __restrict__ Ae, bf16_t* __restrict__ Adil,
                       float* __restrict__ cond_all, float* __restrict__ cond2) {
    if (blockIdx.x >= 1744) {
        __shared__ f32x4 en_s[1024];
        __shared__ f32x4 red[1024];
        int bi = blockIdx.x - 1744;
        int i = bi >> 4;            // 0..30
        int n = (bi >> 2) & 3;
        int og = bi & 3;
        int tid = threadIdx.x;
        const f32x4* ep = (const f32x4*)(en + (size_t)n * 4096);
        for (int idx = tid; idx < 1024; idx += 256) en_s[idx] = ep[idx];
        __syncthreads();
        int o_loc = tid >> 2, part = tid & 3;
        int o = og * 64 + o_loc;
        const float* W = (i < 30) ? cond_w + ((size_t)i * 256 + o) * 256
                                  : end2_w + (size_t)o * 256;
        const float* Wp = W + part * 64;
        f32x4 a0 = {0.f,0.f,0.f,0.f}, a1 = a0, a2 = a0, a3 = a0;
        for (int c = 0; c < 64; c += 4) {
            f32x4 wv = *(const f32x4*)(Wp + c);
            int cg2 = part * 64 + c;
            #pragma unroll
            for (int cc = 0; cc < 4; ++cc) {
                float wf = wv[cc];
                a0 += wf * en_s[(cg2 + cc) * 4 + 0];
                a1 += wf * en_s[(cg2 + cc) * 4 + 1];
                a2 += wf * en_s[(cg2 + cc) * 4 + 2];
                a3 += wf * en_s[(cg2 + cc) * 4 + 3];
            }
        }
        red[tid * 4 + 0] = a0; red[tid * 4 + 1] = a1;
        red[tid * 4 + 2] = a2; red[tid * 4 + 3] = a3;
        __syncthreads();
        if (tid < 64) {
            int o2 = og * 64 + tid;
            float bias = (i < 30) ? 0.f : end2_b[o2];
            float* dst = (i < 30) ? cond_all + (((size_t)i * 4 + n) * 256 + o2) * 16
                                  : cond2 + ((size_t)n * 256 + o2) * 16;
            f32x4* d4 = (f32x4*)dst;
            #pragma unroll
            for (int t = 0; t < 4; ++t) {
                f32x4 s = red[(tid * 4 + 0) * 4 + t] + red[(tid * 4 + 1) * 4 + t]
                        + red[(tid * 4 + 2) * 4 + t] + red[(tid * 4 + 3) * 4 + t];
                d4[t] = s + bias;
            }
        }
        return;
    }
    int g = blockIdx.x * 256 + threadIdx.x;
    if (g < 61440) { conv8(rw, Ares, g, 128, 128); return; }
    g -= 61440;
    if (g < 122880) { conv8(kw, Askp, g, 256, 128); return; }
    g -= 122880;
    if (g < 4096) { conv8(s1w, A1, g, 128, 256); return; }
    g -= 4096;
    if (g < 4096) { conv8(s2w, A2, g, 256, 128); return; }
    g -= 4096;
    if (g < 8192) { conv8(e1w, Ae, g, 256, 256); return; }
    g -= 8192;
    {   // dil_w -> per-layer A[256][256], 8 elems/thread (64B span, stride-2 pick)
        int lay = g >> 13, r = g & 8191;
        int lane = r & 63, rest = r >> 6;
        int kb = rest & 7, mt = rest >> 3;
        int m = mt * 16 + (lane & 15);
        int k0 = kb * 32 + ((lane >> 4) << 3);
        int sel = (k0 < 128) ? 0 : 1;
        int kk = (k0 < 128) ? k0 : k0 - 128;
        const float* s = dwt + (((size_t)lay * 256 + m) * 128 + kk) * 2;
        f32x4 c0 = *(const f32x4*)(s);
        f32x4 c1 = *(const f32x4*)(s + 4);
        f32x4 c2 = *(const f32x4*)(s + 8);
        f32x4 c3 = *(const f32x4*)(s + 12);
        bf16x8 o;
        o[0] = (bf16_t)c0[sel];     o[1] = (bf16_t)c0[2 + sel];
        o[2] = (bf16_t)c1[sel];     o[3] = (bf16_t)c1[2 + sel];
        o[4] = (bf16_t)c2[sel];     o[5] = (bf16_t)c2[2 + sel];
        o[6] = (bf16_t)c3[sel];     o[7] = (bf16_t)c3[2 + sel];
        *(bf16x8*)(Adil + (size_t)lay * 65536 + (size_t)r * 8) = o;
    }
}

// ---------------- start: l0 = start1@x ; s0 = start2@l0 (t>=4096) ----------------
__global__ __launch_bounds__(512, 4) void k_start(
    const float* __restrict__ x, bf16_t* __restrict__ la, float* __restrict__ sbuf,
    const bf16_t* __restrict__ A1, const bf16_t* __restrict__ A2, int t_base)
{
    __shared__ __align__(16) bf16_t xt[64 * PX];
    __shared__ __align__(16) bf16_t l0[64 * PL];
    int tid = threadIdx.x;
    int n = blockIdx.y, t0 = t_base + blockIdx.x * 64;
    int lane = tid & 63, w = tid >> 6, i16 = lane & 15, q = lane >> 4;
    f32x4 z = {0.f,0.f,0.f,0.f};
    {
        int t = tid & 63;
        for (int c = tid >> 6; c < 256; c += 8)
            xt[t * PX + c] = (bf16_t)x[((size_t)n * 256 + c) * 8192 + t0 + t];
    }
    __syncthreads();
    f32x4 acc[4] = {z,z,z,z};
    #pragma unroll
    for (int kb = 0; kb < 8; ++kb) {
        int koff = kb * 32 + q * 8;
        bf16x8 bf[4];
        #pragma unroll
        for (int nt = 0; nt < 4; ++nt)
            bf[nt] = *(const bf16x8*)(xt + (nt * 16 + i16) * PX + koff);
        bf16x8 af = *(const bf16x8*)(A1 + (((size_t)w * 8 + kb) * 64 + lane) * 8);
        #pragma unroll
        for (int nt = 0; nt < 4; ++nt) acc[nt] = mfma16(af, bf[nt], acc[nt]);
    }
    #pragma unroll
    for (int nt = 0; nt < 4; ++nt)
        #pragma unroll
        for (int j = 0; j < 4; ++j)
            l0[(nt * 16 + i16) * PL + w * 16 + q * 4 + j] = (bf16_t)acc[nt][j];
    __syncthreads();
    {
        int r = tid >> 4, col = (tid & 15) * 8;
        #pragma unroll
        for (int p = 0; p < 2; ++p) {
            int rr = r + p * 32;
            *(i32x4*)(la + ((size_t)n * 8192 + t0 + rr) * 128 + col) =
                *(const i32x4*)(l0 + rr * PL + col);
        }
    }
    if (t0 >= 4096) {
        f32x4 a2[2][4] = {{z,z,z,z},{z,z,z,z}};
        #pragma unroll
        for (int kb = 0; kb < 4; ++kb) {
            int koff = kb * 32 + q * 8;
            bf16x8 bf[4];
            #pragma unroll
            for (int nt = 0; nt < 4; ++nt)
                bf[nt] = *(const bf16x8*)(l0 + (nt * 16 + i16) * PL + koff);
            #pragma unroll
            for (int mt2 = 0; mt2 < 2; ++mt2) {
                bf16x8 af = *(const bf16x8*)(A2 + ((((size_t)2 * w + mt2) * 4 + kb) * 64 + lane) * 8);
                #pragma unroll
                for (int nt = 0; nt < 4; ++nt) a2[mt2][nt] = mfma16(af, bf[nt], a2[mt2][nt]);
            }
        }
        float* sp = sbuf + (size_t)n * 256 * 4096 + (t0 - 4096);
        #pragma unroll
        for (int mt2 = 0; mt2 < 2; ++mt2)
            #pragma unroll
            for (int nt = 0; nt < 4; ++nt)
                #pragma unroll
                for (int j = 0; j < 4; ++j) {
                    int o = (2 * w + mt2) * 16 + q * 4 + j;
                    sp[(size_t)o * 4096 + nt * 16 + i16] = a2[mt2][nt][j];
                }
    }
}

// ---------------- fused 6 small-dil layers (dil 1..32), halo-recompute ----------
// r9 geometry (128 owned + 64 halo, double-buffer, 6 chunks) but 1024 threads /
// 16 waves: wave w -> (wo = w>>1 owns out-rows wo*16 & (wo+8)*16, ntf = w&1 owns
// one 16-row t-slab). Half the MFMA+gate work per wave, same per-block totals,
// 2x waves/CU. sm2 ping-pong: ONE barrier/chunk + one per layer-end.
// Row r <-> t = t0 - 64 + r. Halo rows garbage-but-contained (clamped del reads).
template<int USEG>
__global__ __launch_bounds__(1024, 4) void k_fuse(
    const bf16_t* __restrict__ l_in, bf16_t* __restrict__ l_out,
    bf16_t* __restrict__ G,
    const bf16_t* __restrict__ Adil, const bf16_t* __restrict__ Ares,
    const float* __restrict__ condA, int aG, int g0)
{
    __shared__ __align__(16) bf16_t bufA[192 * PL];
    __shared__ __align__(16) bf16_t bufB[192 * PL];
    __shared__ __align__(16) bf16_t sm2[2][32 * PL];
    int tid = threadIdx.x;
    int n = blockIdx.y, t0 = aG + blockIdx.x * 128;
    int lane = tid & 63, w = tid >> 6;       // w in 0..15
    int wo = w >> 1, ntf = w & 1;
    int i16 = lane & 15, q = lane >> 4;
    f32x4 z = {0.f,0.f,0.f,0.f};
    int c_base = wo * 16 + q * 4;
    size_t base = (size_t)n * 8192;
    // stage rows [t0-64, t0+128) -> bufA (192 rows; t<0 -> zeros, causal pad)
    {
        int rr0 = tid >> 4, col = (tid & 15) * 8;
        for (int rr = rr0; rr < 192; rr += 64) {
            int t = t0 - 64 + rr;
            i32x4 v = {0, 0, 0, 0};
            if (t >= 0) v = *(const i32x4*)(l_in + (base + t) * 128 + col);
            *(i32x4*)(bufA + rr * PL + col) = v;
        }
    }
    bf16_t* bin = bufA;
    bf16_t* bout = bufB;
    barrier_nodrain();
    int p = 0;
    #pragma unroll 1
    for (int k = 0; k < 6; ++k) {
        int i = g0 + k;
        int d = 1 << k;
        const bf16x8* AdF = (const bf16x8*)(Adil + (size_t)i * 65536);
        const bf16x8* ArF = (const bf16x8*)(Ares + (size_t)i * 16384);
        const float* cond = condA + ((size_t)i * 4 + n) * 4096;
        bf16_t* Gl = G + (size_t)i * (4ull * 4096 * 128);
        float cv_s[4], cv_t[4];
        #pragma unroll
        for (int j = 0; j < 4; ++j) {
            cv_s[j] = cond[(c_base + j) * 16 + i16];
            cv_t[j] = cond[(c_base + j + 128) * 16 + i16];
        }
        bf16x8 a_s[8], a_t[8];
        #pragma unroll
        for (int kb = 0; kb < 8; ++kb) {
            a_s[kb] = AdF[((size_t)wo * 8 + kb) * 64 + lane];
            a_t[kb] = AdF[((size_t)(wo + 8) * 8 + kb) * 64 + lane];
        }
        bf16x8 ar[4];
        #pragma unroll
        for (int kb = 0; kb < 4; ++kb)
            ar[kb] = ArF[((size_t)wo * 4 + kb) * 64 + lane];
        #pragma unroll 1
        for (int r0 = 0; r0 < 192; r0 += 32) {
            int rr = r0 + ntf * 16 + i16;
            int dr = rr - d; if (dr < 0) dr = 0;  // clamped: garbage stays contained
            // GEMM1 (this wave's slab): 16 MFMA
            f32x4 accs = z, acct = z;
            #pragma unroll
            for (int kb = 0; kb < 8; ++kb) {
                int koff = (kb & 3) * 32 + q * 8;
                const bf16_t* brow = (kb < 4) ? (bin + dr * PL) : (bin + rr * PL);
                bf16x8 bf = *(const bf16x8*)(brow + koff);
                accs = mfma16(a_s[kb], bf, accs);
                acct = mfma16(a_t[kb], bf, acct);
            }
            // gate -> sm2[p]
            bf16_t* s2 = sm2[p];
            {
                bf16x4 g4;
                #pragma unroll
                for (int j = 0; j < 4; ++j) {
                    float vlo = accs[j] + cv_s[j];
                    float vhi = acct[j] + cv_t[j];
                    float sg = 1.0f / (1.0f + __expf(-vlo));
                    float th = 1.0f - 2.0f / (1.0f + __expf(2.0f * vhi));
                    g4[j] = (bf16_t)(sg * th);
                }
                *(bf16x4*)(s2 + (ntf * 16 + i16) * PL + c_base) = g4;
            }
            barrier_nodrain();   // ONE barrier/chunk: gate visible, GEMM1 reads done
            int t_chunk = t0 + (r0 - 64);
            if (USEG && r0 >= 64 && t_chunk >= 4096) {
                // gate tile -> G in fragment order (bf16x4/thread, coalesced)
                int u = tid >> 1, half = tid & 1;
                int tt = ((u & 256) >> 4) + (u & 15);
                int cc = ((u >> 6) & 3) * 32 + ((u >> 4) & 3) * 8 + half * 4;
                *(bf16x4*)(Gl + ((size_t)n * 4096 + (t_chunk - 4096)) * 128
                              + (size_t)tid * 4)
                    = *(const bf16x4*)(s2 + tt * PL + cc);
            }
            // res GEMM + residual add -> bout (this wave's slab): 4 MFMA
            f32x4 acc2 = z;
            #pragma unroll
            for (int kb = 0; kb < 4; ++kb) {
                bf16x8 bf = *(const bf16x8*)(s2 + (ntf * 16 + i16) * PL + kb * 32 + q * 8);
                acc2 = mfma16(ar[kb], bf, acc2);
            }
            {
                bf16x4 lv = *(const bf16x4*)(bin + rr * PL + c_base);
                bf16x4 o4;
                #pragma unroll
                for (int j = 0; j < 4; ++j)
                    o4[j] = (bf16_t)((float)lv[j] + acc2[j]);
                *(bf16x4*)(bout + rr * PL + c_base) = o4;
            }
            p ^= 1;
        }
        barrier_nodrain();   // layer-end: all bout writes visible before next layer
        bf16_t* tsw = bin; bin = bout; bout = tsw;
    }
    // final: rows [64,192) of bin -> l_out [t0, t0+128)
    {
        int rr0 = tid >> 4, col = (tid & 15) * 8;
        for (int rr = 64 + rr0; rr < 192; rr += 64) {
            *(i32x4*)(l_out + (base + t0 - 64 + rr) * 128 + col) =
                *(const i32x4*)(bin + rr * PL + col);
        }
    }
}

// ---------------- single layer, TT=32 (r3-proven; used for dil>=64) ----------------
template<int USEG>
__global__ __launch_bounds__(512, 4) void k_layer(
    const bf16_t* __restrict__ l_in, bf16_t* __restrict__ l_out,
    float* __restrict__ sbuf, bf16_t* __restrict__ Gl,
    const bf16_t* __restrict__ Ad, const bf16_t* __restrict__ Ar,
    const bf16_t* __restrict__ Ak, const float* __restrict__ condL,
    int dil, int t_base, int do_res)
{
    __shared__ __align__(16) bf16_t smA[64 * PL];   // staging (cur|del or combined)
    __shared__ __align__(16) bf16_t sm2[32 * PL];   // gate
    int tid = threadIdx.x;
    int n = blockIdx.y, t0 = t_base + blockIdx.x * 32;
    int lane = tid & 63, w = tid >> 6, i16 = lane & 15, q = lane >> 4;
    f32x4 z = {0.f,0.f,0.f,0.f};
    const float* cond = condL + (size_t)n * 4096;
    int r = tid >> 4, col = (tid & 15) * 8;
    int c_base = w * 16 + q * 4;
    size_t base = (size_t)n * 8192;

    float cv_s[4], cv_t[4];
    #pragma unroll
    for (int j = 0; j < 4; ++j) {
        cv_s[j] = cond[(c_base + j) * 16 + i16];
        cv_t[j] = cond[(c_base + j + 128) * 16 + i16];
    }
    const bf16x8* AdF = (const bf16x8*)Ad;
    bf16x8 a_s[8], a_t[8];
    #pragma unroll
    for (int kb = 0; kb < 8; ++kb) {
        a_s[kb] = AdF[((size_t)w * 8 + kb) * 64 + lane];
        a_t[kb] = AdF[((size_t)(w + 8) * 8 + kb) * 64 + lane];
    }

    const bf16_t* curp;
    const bf16_t* delp;
    if (dil < 32) {
        int cnt = (32 + dil) * 16;
        for (int idx = tid; idx < cnt; idx += 512) {
            int rr = idx >> 4, c2 = (idx & 15) * 8;
            *(i32x4*)(smA + rr * PL + c2) =
                *(const i32x4*)(l_in + (base + t0 - dil + rr) * 128 + c2);
        }
        delp = smA; curp = smA + dil * PL;
    } else {
        *(i32x4*)(smA + r * PL + col) =
            *(const i32x4*)(l_in + (base + t0 + r) * 128 + col);
        int gp = t0 - dil + r;
        i32x4 v = {0, 0, 0, 0};
        if (gp >= 0) v = *(const i32x4*)(l_in + (base + gp) * 128 + col);
        *(i32x4*)(smA + (32 + r) * PL + col) = v;
        curp = smA; delp = smA + 32 * PL;
    }
    barrier_nodrain();

    f32x4 accs[2] = {z,z}, acct[2] = {z,z};
    #pragma unroll
    for (int kb = 0; kb < 8; ++kb) {
        const bf16_t* bsrc = (kb < 4) ? delp : curp;
        int koff = (kb & 3) * 32 + q * 8;
        bf16x8 bf[2];
        #pragma unroll
        for (int nt = 0; nt < 2; ++nt)
            bf[nt] = *(const bf16x8*)(bsrc + (nt * 16 + i16) * PL + koff);
        #pragma unroll
        for (int nt = 0; nt < 2; ++nt) {
            accs[nt] = mfma16(a_s[kb], bf[nt], accs[nt]);
            acct[nt] = mfma16(a_t[kb], bf[nt], acct[nt]);
        }
    }

    const bf16x8* ArF = (const bf16x8*)Ar;
    bf16x8 ar[4];
    if (do_res) {
        #pragma unroll
        for (int kb = 0; kb < 4; ++kb)
            ar[kb] = ArF[((size_t)w * 4 + kb) * 64 + lane];
    }

    {
        #pragma unroll
        for (int nt = 0; nt < 2; ++nt) {
            bf16x4 g4;
            #pragma unroll
            for (int j = 0; j < 4; ++j) {
                float vlo = accs[nt][j] + cv_s[j];
                float vhi = acct[nt][j] + cv_t[j];
                float sg = 1.0f / (1.0f + __expf(-vlo));
                float th = 1.0f - 2.0f / (1.0f + __expf(2.0f * vhi));
                g4[j] = (bf16_t)(sg * th);
            }
            *(bf16x4*)(sm2 + (nt * 16 + i16) * PL + c_base) = g4;
        }
    }
    barrier_nodrain();

    if (USEG) {
        if (t0 >= 4096) {
            int tt = ((tid & 256) >> 4) + (tid & 15);
            int cc = ((tid >> 6) & 3) * 32 + ((tid >> 4) & 3) * 8;
            bf16x8 gv = *(const bf16x8*)(sm2 + tt * PL + cc);
            *(bf16x8*)(Gl + ((size_t)n * 4096 + (t0 - 4096)) * 128 + tid * 8) = gv;
        }
    }

    f32x4 acc2[2] = {z,z};
    if (do_res || !USEG) {
        int do_skip = (!USEG) && (t0 >= 4096);
        f32x4 acc3[2][2] = {{z,z},{z,z}};
        const bf16x8* AkF = (const bf16x8*)Ak;
        #pragma unroll
        for (int kb = 0; kb < 4; ++kb) {
            int koff = kb * 32 + q * 8;
            bf16x8 bf[2];
            #pragma unroll
            for (int nt = 0; nt < 2; ++nt)
                bf[nt] = *(const bf16x8*)(sm2 + (nt * 16 + i16) * PL + koff);
            if (do_res) {
                #pragma unroll
                for (int nt = 0; nt < 2; ++nt) acc2[nt] = mfma16(ar[kb], bf[nt], acc2[nt]);
            }
            if (do_skip) {
                #pragma unroll
                for (int mt2 = 0; mt2 < 2; ++mt2) {
                    bf16x8 ak = AkF[((size_t)(2 * w + mt2) * 4 + kb) * 64 + lane];
                    #pragma unroll
                    for (int nt = 0; nt < 2; ++nt)
                        acc3[mt2][nt] = mfma16(ak, bf[nt], acc3[mt2][nt]);
                }
            }
        }
        if (do_skip) {
            float* sp = sbuf + (size_t)n * 256 * 4096 + (t0 - 4096);
            #pragma unroll
            for (int mt2 = 0; mt2 < 2; ++mt2)
                #pragma unroll
                for (int nt = 0; nt < 2; ++nt)
                    #pragma unroll
                    for (int j = 0; j < 4; ++j) {
                        int o = (2 * w + mt2) * 16 + q * 4 + j;
                        sp[(size_t)o * 4096 + nt * 16 + i16] += acc3[mt2][nt][j];
                    }
        }
    }

    if (do_res) {
        #pragma unroll
        for (int nt = 0; nt < 2; ++nt) {
            int trow = (nt * 16 + i16) * PL;
            bf16x4 lv = *(const bf16x4*)(curp + trow + c_base);
            bf16x4 o4;
            #pragma unroll
            for (int j = 0; j < 4; ++j)
                o4[j] = (bf16_t)((float)lv[j] + acc2[nt][j]);
            *(bf16x4*)(l_out + (base + t0 + nt * 16 + i16) * 128 + c_base) = o4;
        }
    }
}

// ---------------- deferred skip mega-GEMM: s += sum_i skip_i @ g_i ----------------
#define SKIP_HALF(I, AKU, AKP, GW0, GW1)                                        \
    {                                                                           \
        const int i_ = (I);                                                     \
        if (i_ + 1 < 30) {                                                      \
            bf16_t* db = gbuf[(i_ + 1) & 1];                                    \
            *(i32x4*)(db + tid * 8) = GW0;                                      \
            *(i32x4*)(db + 4096 + tid * 8) = GW1;                               \
        }                                                                       \
        if (i_ + 3 < 30) {                                                      \
            const bf16_t* srcp = gb + (size_t)(i_ + 3) * GLS;                   \
            GW0 = *(const i32x4*)(srcp);                                        \
            GW1 = *(const i32x4*)(srcp + 4096);                                 \
        }                                                                       \
        if (i_ + 1 < 30) {                                                      \
            const bf16x8* An = (const bf16x8*)(Askp + (size_t)(i_ + 1) * 32768);\
            _Pragma("unroll")                                                   \
            for (int kb = 0; kb < 4; ++kb) {                                    \
                AKP[2 * kb]     = An[fi0 + kb * 64];                            \
                AKP[2 * kb + 1] = An[fi1 + kb * 64];                            \
            }                                                                   \
        }                                                                       \
        const bf16_t* gp_ = gbuf[i_ & 1];                                       \
        _Pragma("unroll")                                                       \
        for (int kb = 0; kb < 4; ++kb) {                                        \
            _Pragma("unroll")                                                   \
            for (int nt = 0; nt < 4; ++nt) {                                    \
                bf16x8 bfv = *(const bf16x8*)(gp_ + (nt >> 1) * 4096 +          \
                              (((nt & 1) * 4 + kb) * 64 + lane) * 8);           \
                acc[0][nt] = mfma16(AKU[2 * kb], bfv, acc[0][nt]);              \
                acc[1][nt] = mfma16(AKU[2 * kb + 1], bfv, acc[1][nt]);          \
            }                                                                   \
        }                                                                       \
        if (i_ + 1 < 30) {                                                      \
            asm volatile("s_waitcnt lgkmcnt(0)" ::: "memory");                  \
            __builtin_amdgcn_sched_barrier(0);                                  \
            __builtin_amdgcn_s_barrier();                                       \
            __builtin_amdgcn_sched_barrier(0);                                  \
        }                                                                       \
    }

__global__ __launch_bounds__(512, 2) void k_skip(
    const bf16_t* __restrict__ G, float* __restrict__ sbuf,
    const bf16_t* __restrict__ Askp)
{
    __shared__ __align__(16) bf16_t gbuf[2][8192];
    int tid = threadIdx.x;
    int n = blockIdx.y, t0 = blockIdx.x * 64;
    int lane = tid & 63, w = tid >> 6, i16 = lane & 15, q = lane >> 4;
    f32x4 z = {0.f,0.f,0.f,0.f};
    f32x4 acc[2][4] = {{z,z,z,z},{z,z,z,z}};
    const size_t GLS = (size_t)4 * 4096 * 128;   // per-layer stride in G (elems)
    const bf16_t* gb = G + ((size_t)n * 4096 + t0) * 128 + tid * 8;
    int fi0 = (2 * w) * 256 + lane;
    int fi1 = fi0 + 256;
    bf16x8 akA[8], akB[8];
    {
        const bf16x8* A0 = (const bf16x8*)Askp;
        #pragma unroll
        for (int kb = 0; kb < 4; ++kb) {
            akA[2 * kb]     = A0[fi0 + kb * 64];
            akA[2 * kb + 1] = A0[fi1 + kb * 64];
        }
    }
    i32x4 gA0, gA1, gB0, gB1;
    {
        i32x4 t0v = *(const i32x4*)(gb);
        i32x4 t1v = *(const i32x4*)(gb + 4096);
        *(i32x4*)(gbuf[0] + tid * 8) = t0v;
        *(i32x4*)(gbuf[0] + 4096 + tid * 8) = t1v;
    }
    gA0 = *(const i32x4*)(gb + 1 * GLS);
    gA1 = *(const i32x4*)(gb + 1 * GLS + 4096);
    gB0 = *(const i32x4*)(gb + 2 * GLS);
    gB1 = *(const i32x4*)(gb + 2 * GLS + 4096);
    __syncthreads();   // prologue: single full drain
    #pragma unroll 1
    for (int ii = 0; ii < 30; ii += 2) {
        SKIP_HALF(ii,     akA, akB, gA0, gA1)
        SKIP_HALF(ii + 1, akB, akA, gB0, gB1)
    }
    float* sp = sbuf + (size_t)n * 256 * 4096 + t0;
    #pragma unroll
    for (int mt2 = 0; mt2 < 2; ++mt2)
        #pragma unroll
        for (int nt = 0; nt < 4; ++nt)
            #pragma unroll
            for (int j = 0; j < 4; ++j) {
                int o = (2 * w + mt2) * 16 + q * 4 + j;
                sp[(size_t)o * 4096 + nt * 16 + i16] += acc[mt2][nt][j];
            }
}

// ---------------- end: out = relu(end1@relu(s) + b1 + cond2_tiled) ----------------
__global__ __launch_bounds__(512) void k_end(
    const float* __restrict__ sbuf, float* __restrict__ out,
    const bf16_t* __restrict__ Ae, const float* __restrict__ cond2,
    const float* __restrict__ b1)
{
    __shared__ __align__(16) bf16_t st[64 * PX];
    __shared__ float c2[4096];
    __shared__ float b1s[256];
    int tid = threadIdx.x;
    int n = blockIdx.y, t0 = blockIdx.x * 64;
    int lane = tid & 63, w = tid >> 6, i16 = lane & 15, q = lane >> 4;
    f32x4 z = {0.f,0.f,0.f,0.f};
    {
        int t = tid & 63;
        for (int c = tid >> 6; c < 256; c += 8) {
            float v = sbuf[((size_t)n * 256 + c) * 4096 + t0 + t];
            st[t * PX + c] = (bf16_t)fmaxf(v, 0.f);
        }
        const f32x4* cc = (const f32x4*)(cond2 + (size_t)n * 4096);
        for (int idx = tid; idx < 1024; idx += 512) ((f32x4*)c2)[idx] = cc[idx];
        if (tid < 64) ((f32x4*)b1s)[tid] = ((const f32x4*)b1)[tid];
    }
    __syncthreads();
    f32x4 acc[2][4] = {{z,z,z,z},{z,z,z,z}};
    #pragma unroll
    for (int kb = 0; kb < 8; ++kb) {
        int koff = kb * 32 + q * 8;
        bf16x8 bf[4];
        #pragma unroll
        for (int nt = 0; nt < 4; ++nt)
            bf[nt] = *(const bf16x8*)(st + (nt * 16 + i16) * PX + koff);
        #pragma unroll
        for (int mt2 = 0; mt2 < 2; ++mt2) {
            bf16x8 af = *(const bf16x8*)(Ae + ((((size_t)2 * w + mt2) * 8 + kb) * 64 + lane) * 8);
            #pragma unroll
            for (int nt = 0; nt < 4; ++nt) acc[mt2][nt] = mfma16(af, bf[nt], acc[mt2][nt]);
        }
    }
    #pragma unroll
    for (int mt2 = 0; mt2 < 2; ++mt2)
        #pragma unroll
        for (int j = 0; j < 4; ++j) {
            int o = (2 * w + mt2) * 16 + q * 4 + j;
            float bb = b1s[o] + c2[o * 16 + i16];
            #pragma unroll
            for (int nt = 0; nt < 4; ++nt) {
                float v = acc[mt2][nt][j] + bb;
                out[((size_t)n * 256 + o) * 4096 + t0 + nt * 16 + i16] = fmaxf(v, 0.f);
            }
        }
}

extern "C" void kernel_launch(void* const* d_in, const int* in_sizes, int n_in,
                              void* d_out, int out_size, void* d_ws, size_t ws_size,
                              hipStream_t stream) {
    const float* x   = (const float*)d_in[0];
    const float* en  = (const float*)d_in[1];
    const float* s1w = (const float*)d_in[2];
    const float* s2w = (const float*)d_in[3];
    const float* cw  = (const float*)d_in[4];
    const float* dw  = (const float*)d_in[5];
    const float* rw  = (const float*)d_in[6];
    const float* kw  = (const float*)d_in[7];
    const float* e1w = (const float*)d_in[8];
    const float* e1b = (const float*)d_in[9];
    const float* e2w = (const float*)d_in[10];
    const float* e2b = (const float*)d_in[11];
    float* out = (float*)d_out;

    char* p = (char*)d_ws;
    auto take = [&](size_t bytes) {
        char* r = p;
        p += (bytes + 255) & ~(size_t)255;
        return r;
    };
    bf16_t* A1   = (bf16_t*)take((size_t)128 * 256 * 2);
    bf16_t* A2   = (bf16_t*)take((size_t)256 * 128 * 2);
    bf16_t* Ae   = (bf16_t*)take((size_t)256 * 256 * 2);
    bf16_t* Adil = (bf16_t*)take((size_t)30 * 65536 * 2);
    bf16_t* Ares = (bf16_t*)take((size_t)30 * 16384 * 2);
    bf16_t* Askp = (bf16_t*)take((size_t)30 * 32768 * 2);
    float*  condA= (float*)take((size_t)30 * 16384 * 4);
    float*  cond2= (float*)take((size_t)16384 * 4);
    bf16_t* la   = (bf16_t*)take((size_t)4 * 8192 * 128 * 2);
    bf16_t* lb   = (bf16_t*)take((size_t)4 * 8192 * 128 * 2);
    float*  sbuf = (float*)take((size_t)4 * 256 * 4096 * 4);
    bf16_t* G    = (bf16_t*)take((size_t)30 * 4 * 4096 * 128 * 2);  // last
    bool useG = ((size_t)(p - (char*)d_ws) <= ws_size);

    k_prep<<<2240, 256, 0, stream>>>(rw, kw, s1w, s2w, e1w, dw,
                                     cw, e2w, e2b, en,
                                     Ares, Askp, A1, A2, Ae, Adil, condA, cond2);

    // causal trim table (host)
    int a[30];
    a[29] = 4096;
    for (int i = 28; i >= 0; --i) {
        int nx = a[i + 1] - (1 << ((i + 1) % 10));
        a[i] = nx < 4096 ? (nx & ~63) : 4096;
    }

    k_start<<<dim3(127, 4), 512, 0, stream>>>(x, la, sbuf, A1, A2, 64);

    bf16_t* src = la;
    bf16_t* dst = lb;
    if (useG) {
        for (int g = 0; g < 3; ++g) {
            int g0 = g * 10;
            int aG = a[g0] & ~127;
            dim3 gridF((8192 - aG) / 128, 4);
            k_fuse<1><<<gridF, 1024, 0, stream>>>(src, dst, G, Adil, Ares,
                                                  condA, aG, g0);
            { bf16_t* t = src; src = dst; dst = t; }
            for (int i = g0 + 6; i < g0 + 10; ++i) {
                dim3 grid2((8192 - a[i]) / 32, 4);
                k_layer<1><<<grid2, 512, 0, stream>>>(src, dst, sbuf,
                    G + (size_t)i * 4 * 4096 * 128,
                    Adil + (size_t)i * 65536, Ares + (size_t)i * 16384,
                    Askp + (size_t)i * 32768, condA + (size_t)i * 16384,
                    1 << (i % 10), a[i], i < 29 ? 1 : 0);
                bf16_t* t = src; src = dst; dst = t;
            }
        }
        k_skip<<<dim3(64, 4), 512, 0, stream>>>(G, sbuf, Askp);
    } else {
        for (int i = 0; i < 30; ++i) {
            dim3 grid((8192 - a[i]) / 32, 4);
            k_layer<0><<<grid, 512, 0, stream>>>(src, dst, sbuf, (bf16_t*)nullptr,
                Adil + (size_t)i * 65536, Ares + (size_t)i * 16384,
                Askp + (size_t)i * 32768, condA + (size_t)i * 16384,
                1 << (i % 10), a[i], i < 29 ? 1 : 0);
            bf16_t* t = src; src = dst; dst = t;
        }
    }
    k_end<<<dim3(64, 4), 512, 0, stream>>>(sbuf, out, Ae, cond2, e1b);
}

// Round 12
// 566.387 us; speedup vs baseline: 1.2310x; 1.1090x over previous
//
#include <hip/hip_runtime.h>

typedef __bf16 bf16_t;
typedef __bf16 bf16x8 __attribute__((ext_vector_type(8)));
typedef __bf16 bf16x4 __attribute__((ext_vector_type(4)));
typedef float  f32x4  __attribute__((ext_vector_type(4)));
typedef int    i32x4  __attribute__((ext_vector_type(4)));

#define PL 136   // padded row stride (elems) for [t][128] bf16 tiles (272B = 16B-aligned)
#define PX 264   // padded row stride (elems) for [t][256] bf16 tiles

__device__ __forceinline__ f32x4 mfma16(bf16x8 a, bf16x8 b, f32x4 c) {
    return __builtin_amdgcn_mfma_f32_16x16x32_bf16(a, b, c, 0, 0, 0);
}

// barrier that drains LDS ops only — keeps global (vmcnt) loads in flight.
__device__ __forceinline__ void barrier_nodrain() {
    asm volatile("s_waitcnt lgkmcnt(0)" ::: "memory");
    __builtin_amdgcn_sched_barrier(0);
    __builtin_amdgcn_s_barrier();
    __builtin_amdgcn_sched_barrier(0);
}

// sigmoid(a)*tanh(b) with shared denominators: ONE division instead of two.
// eb clamped (min(-2b,80)) so b -> -inf degrades to -1 gracefully (no inf/inf NaN).
__device__ __forceinline__ float gatef(float a, float b) {
    float ea = __expf(-a);
    float eb = __expf(fminf(-2.f * b, 80.f));
    return (1.f - eb) / ((1.f + ea) * (1.f + eb));
}

// ---------------- merged prep: weight conversion + conditioning ----------------
__device__ __forceinline__ void conv8(const float* __restrict__ src,
                                      bf16_t* __restrict__ dst,
                                      int g, int M, int K) {
    int MK8 = (M * K) >> 3;
    int lay = g / MK8;
    int r = g - lay * MK8;
    int lane = r & 63, rest = r >> 6;
    int KB = K >> 5;
    int kb = rest % KB, mt = rest / KB;
    int m = mt * 16 + (lane & 15);
    int k = kb * 32 + ((lane >> 4) << 3);
    const float* s = src + (size_t)lay * M * K + (size_t)m * K + k;
    f32x4 v0 = *(const f32x4*)s;
    f32x4 v1 = *(const f32x4*)(s + 4);
    bf16x8 o;
    o[0] = (bf16_t)v0[0]; o[1] = (bf16_t)v0[1]; o[2] = (bf16_t)v0[2]; o[3] = (bf16_t)v0[3];
    o[4] = (bf16_t)v1[0]; o[5] = (bf16_t)v1[1]; o[6] = (bf16_t)v1[2]; o[7] = (bf16_t)v1[3];
    *(bf16x8*)(dst + (size_t)g * 8) = o;
}

__global__ __launch_bounds__(256) void k_prep(
                       const float* __restrict__ rw, const float* __restrict__ kw,
                       const float* __restrict__ s1w, const float* __restrict__ s2w,
                       const float* __restrict__ e1w, const float* __restrict__ dwt,
                       const float* __restrict__ cond_w, const float* __restrict__ end2_w,
                       const float* __restrict__ end2_b, const float* __restrict__ en,
                       bf16_t* __restrict__ Ares, bf16_t* __restrict__ Askp,
                       bf16_t* __restrict__ A1, bf16_t* __restrict__ A2,
                       bf16_t* __restrict__ Ae, bf16_t* __restrict__ Adil,
                       float* __restrict__ cond_all, float* __restrict__ cond2) {
    if (blockIdx.x >= 1744) {
        __shared__ f32x4 en_s[1024];
        __shared__ f32x4 red[1024];
        int bi = blockIdx.x - 1744;
        int i = bi >> 4;            // 0..30
        int n = (bi >> 2) & 3;
        int og = bi & 3;
        int tid = threadIdx.x;
        const f32x4* ep = (const f32x4*)(en + (size_t)n * 4096);
        for (int idx = tid; idx < 1024; idx += 256) en_s[idx] = ep[idx];
        __syncthreads();
        int o_loc = tid >> 2, part = tid & 3;
        int o = og * 64 + o_loc;
        const float* W = (i < 30) ? cond_w + ((size_t)i * 256 + o) * 256
                                  : end2_w + (size_t)o * 256;
        const float* Wp = W + part * 64;
        f32x4 a0 = {0.f,0.f,0.f,0.f}, a1 = a0, a2 = a0, a3 = a0;
        for (int c = 0; c < 64; c += 4) {
            f32x4 wv = *(const f32x4*)(Wp + c);
            int cg2 = part * 64 + c;
            #pragma unroll
            for (int cc = 0; cc < 4; ++cc) {
                float wf = wv[cc];
                a0 += wf * en_s[(cg2 + cc) * 4 + 0];
                a1 += wf * en_s[(cg2 + cc) * 4 + 1];
                a2 += wf * en_s[(cg2 + cc) * 4 + 2];
                a3 += wf * en_s[(cg2 + cc) * 4 + 3];
            }
        }
        red[tid * 4 + 0] = a0; red[tid * 4 + 1] = a1;
        red[tid * 4 + 2] = a2; red[tid * 4 + 3] = a3;
        __syncthreads();
        if (tid < 64) {
            int o2 = og * 64 + tid;
            float bias = (i < 30) ? 0.f : end2_b[o2];
            float* dst = (i < 30) ? cond_all + (((size_t)i * 4 + n) * 256 + o2) * 16
                                  : cond2 + ((size_t)n * 256 + o2) * 16;
            f32x4* d4 = (f32x4*)dst;
            #pragma unroll
            for (int t = 0; t < 4; ++t) {
                f32x4 s = red[(tid * 4 + 0) * 4 + t] + red[(tid * 4 + 1) * 4 + t]
                        + red[(tid * 4 + 2) * 4 + t] + red[(tid * 4 + 3) * 4 + t];
                d4[t] = s + bias;
            }
        }
        return;
    }
    int g = blockIdx.x * 256 + threadIdx.x;
    if (g < 61440) { conv8(rw, Ares, g, 128, 128); return; }
    g -= 61440;
    if (g < 122880) { conv8(kw, Askp, g, 256, 128); return; }
    g -= 122880;
    if (g < 4096) { conv8(s1w, A1, g, 128, 256); return; }
    g -= 4096;
    if (g < 4096) { conv8(s2w, A2, g, 256, 128); return; }
    g -= 4096;
    if (g < 8192) { conv8(e1w, Ae, g, 256, 256); return; }
    g -= 8192;
    {   // dil_w -> per-layer A[256][256], 8 elems/thread (64B span, stride-2 pick)
        int lay = g >> 13, r = g & 8191;
        int lane = r & 63, rest = r >> 6;
        int kb = rest & 7, mt = rest >> 3;
        int m = mt * 16 + (lane & 15);
        int k0 = kb * 32 + ((lane >> 4) << 3);
        int sel = (k0 < 128) ? 0 : 1;
        int kk = (k0 < 128) ? k0 : k0 - 128;
        const float* s = dwt + (((size_t)lay * 256 + m) * 128 + kk) * 2;
        f32x4 c0 = *(const f32x4*)(s);
        f32x4 c1 = *(const f32x4*)(s + 4);
        f32x4 c2 = *(const f32x4*)(s + 8);
        f32x4 c3 = *(const f32x4*)(s + 12);
        bf16x8 o;
        o[0] = (bf16_t)c0[sel];     o[1] = (bf16_t)c0[2 + sel];
        o[2] = (bf16_t)c1[sel];     o[3] = (bf16_t)c1[2 + sel];
        o[4] = (bf16_t)c2[sel];     o[5] = (bf16_t)c2[2 + sel];
        o[6] = (bf16_t)c3[sel];     o[7] = (bf16_t)c3[2 + sel];
        *(bf16x8*)(Adil + (size_t)lay * 65536 + (size_t)r * 8) = o;
    }
}

// ---------------- start: l0 = start1@x ; s0 = start2@l0 (t>=4096) ----------------
__global__ __launch_bounds__(512, 4) void k_start(
    const float* __restrict__ x, bf16_t* __restrict__ la, float* __restrict__ sbuf,
    const bf16_t* __restrict__ A1, const bf16_t* __restrict__ A2, int t_base)
{
    __shared__ __align__(16) bf16_t xt[64 * PX];
    __shared__ __align__(16) bf16_t l0[64 * PL];
    int tid = threadIdx.x;
    int n = blockIdx.y, t0 = t_base + blockIdx.x * 64;
    int lane = tid & 63, w = tid >> 6, i16 = lane & 15, q = lane >> 4;
    f32x4 z = {0.f,0.f,0.f,0.f};
    {
        int t = tid & 63;
        for (int c = tid >> 6; c < 256; c += 8)
            xt[t * PX + c] = (bf16_t)x[((size_t)n * 256 + c) * 8192 + t0 + t];
    }
    __syncthreads();
    f32x4 acc[4] = {z,z,z,z};
    #pragma unroll
    for (int kb = 0; kb < 8; ++kb) {
        int koff = kb * 32 + q * 8;
        bf16x8 bf[4];
        #pragma unroll
        for (int nt = 0; nt < 4; ++nt)
            bf[nt] = *(const bf16x8*)(xt + (nt * 16 + i16) * PX + koff);
        bf16x8 af = *(const bf16x8*)(A1 + (((size_t)w * 8 + kb) * 64 + lane) * 8);
        #pragma unroll
        for (int nt = 0; nt < 4; ++nt) acc[nt] = mfma16(af, bf[nt], acc[nt]);
    }
    #pragma unroll
    for (int nt = 0; nt < 4; ++nt)
        #pragma unroll
        for (int j = 0; j < 4; ++j)
            l0[(nt * 16 + i16) * PL + w * 16 + q * 4 + j] = (bf16_t)acc[nt][j];
    __syncthreads();
    {
        int r = tid >> 4, col = (tid & 15) * 8;
        #pragma unroll
        for (int p = 0; p < 2; ++p) {
            int rr = r + p * 32;
            *(i32x4*)(la + ((size_t)n * 8192 + t0 + rr) * 128 + col) =
                *(const i32x4*)(l0 + rr * PL + col);
        }
    }
    if (t0 >= 4096) {
        f32x4 a2[2][4] = {{z,z,z,z},{z,z,z,z}};
        #pragma unroll
        for (int kb = 0; kb < 4; ++kb) {
            int koff = kb * 32 + q * 8;
            bf16x8 bf[4];
            #pragma unroll
            for (int nt = 0; nt < 4; ++nt)
                bf[nt] = *(const bf16x8*)(l0 + (nt * 16 + i16) * PL + koff);
            #pragma unroll
            for (int mt2 = 0; mt2 < 2; ++mt2) {
                bf16x8 af = *(const bf16x8*)(A2 + ((((size_t)2 * w + mt2) * 4 + kb) * 64 + lane) * 8);
                #pragma unroll
                for (int nt = 0; nt < 4; ++nt) a2[mt2][nt] = mfma16(af, bf[nt], a2[mt2][nt]);
            }
        }
        float* sp = sbuf + (size_t)n * 256 * 4096 + (t0 - 4096);
        #pragma unroll
        for (int mt2 = 0; mt2 < 2; ++mt2)
            #pragma unroll
            for (int nt = 0; nt < 4; ++nt)
                #pragma unroll
                for (int j = 0; j < 4; ++j) {
                    int o = (2 * w + mt2) * 16 + q * 4 + j;
                    sp[(size_t)o * 4096 + nt * 16 + i16] = a2[mt2][nt][j];
                }
    }
}

// ---------------- fused 6 small-dil layers (dil 1..32), halo-recompute ----------
// r9 geometry: block owns t in [t0, t0+128) + 64-row halo; l in LDS ping-pong
// (bufA/bufB) across 6 layers. sm2 double-buffered so each chunk needs ONE
// barrier (+1 per layer-end) — dependence structure validated by r11's run.
// Row r <-> t = t0 - 64 + r. Halo rows garbage-but-contained (clamped del reads).
template<int USEG>
__global__ __launch_bounds__(512, 2) void k_fuse(
    const bf16_t* __restrict__ l_in, bf16_t* __restrict__ l_out,
    bf16_t* __restrict__ G,
    const bf16_t* __restrict__ Adil, const bf16_t* __restrict__ Ares,
    const float* __restrict__ condA, int aG, int g0)
{
    __shared__ __align__(16) bf16_t bufA[192 * PL];
    __shared__ __align__(16) bf16_t bufB[192 * PL];
    __shared__ __align__(16) bf16_t sm2[2][32 * PL];
    int tid = threadIdx.x;
    int n = blockIdx.y, t0 = aG + blockIdx.x * 128;
    int lane = tid & 63, w = tid >> 6, i16 = lane & 15, q = lane >> 4;
    f32x4 z = {0.f,0.f,0.f,0.f};
    int c_base = w * 16 + q * 4;
    size_t base = (size_t)n * 8192;
    // stage rows [t0-64, t0+128) -> bufA (192 rows; t<0 -> zeros, causal pad)
    {
        int rr0 = tid >> 4, col = (tid & 15) * 8;
        for (int rr = rr0; rr < 192; rr += 32) {
            int t = t0 - 64 + rr;
            i32x4 v = {0, 0, 0, 0};
            if (t >= 0) v = *(const i32x4*)(l_in + (base + t) * 128 + col);
            *(i32x4*)(bufA + rr * PL + col) = v;
        }
    }
    bf16_t* bin = bufA;
    bf16_t* bout = bufB;
    barrier_nodrain();
    int p = 0;
    #pragma unroll 1
    for (int k = 0; k < 6; ++k) {
        int i = g0 + k;
        int d = 1 << k;
        const bf16x8* AdF = (const bf16x8*)(Adil + (size_t)i * 65536);
        const bf16x8* ArF = (const bf16x8*)(Ares + (size_t)i * 16384);
        const float* cond = condA + ((size_t)i * 4 + n) * 4096;
        bf16_t* Gl = G + (size_t)i * (4ull * 4096 * 128);
        float cv_s[4], cv_t[4];
        #pragma unroll
        for (int j = 0; j < 4; ++j) {
            cv_s[j] = cond[(c_base + j) * 16 + i16];
            cv_t[j] = cond[(c_base + j + 128) * 16 + i16];
        }
        bf16x8 a_s[8], a_t[8];
        #pragma unroll
        for (int kb = 0; kb < 8; ++kb) {
            a_s[kb] = AdF[((size_t)w * 8 + kb) * 64 + lane];
            a_t[kb] = AdF[((size_t)(w + 8) * 8 + kb) * 64 + lane];
        }
        bf16x8 ar[4];
        #pragma unroll
        for (int kb = 0; kb < 4; ++kb)
            ar[kb] = ArF[((size_t)w * 4 + kb) * 64 + lane];
        #pragma unroll 1
        for (int r0 = 0; r0 < 192; r0 += 32) {
            // GEMM1: d-tile = [W_del W_cur] @ [l(r-d); l(r)], M=256 K=256 N=32
            f32x4 accs[2] = {z,z}, acct[2] = {z,z};
            #pragma unroll
            for (int kb = 0; kb < 8; ++kb) {
                int koff = (kb & 3) * 32 + q * 8;
                bf16x8 bf[2];
                #pragma unroll
                for (int nt = 0; nt < 2; ++nt) {
                    int rr = r0 + nt * 16 + i16;
                    int dr = (kb < 4) ? (rr - d) : rr;
                    if (dr < 0) dr = 0;   // clamped: garbage stays in invalid rows
                    bf[nt] = *(const bf16x8*)(bin + dr * PL + koff);
                }
                #pragma unroll
                for (int nt = 0; nt < 2; ++nt) {
                    accs[nt] = mfma16(a_s[kb], bf[nt], accs[nt]);
                    acct[nt] = mfma16(a_t[kb], bf[nt], acct[nt]);
                }
            }
            // gate -> sm2[p]
            bf16_t* s2 = sm2[p];
            #pragma unroll
            for (int nt = 0; nt < 2; ++nt) {
                bf16x4 g4;
                #pragma unroll
                for (int j = 0; j < 4; ++j)
                    g4[j] = (bf16_t)gatef(accs[nt][j] + cv_s[j], acct[nt][j] + cv_t[j]);
                *(bf16x4*)(s2 + (nt * 16 + i16) * PL + c_base) = g4;
            }
            barrier_nodrain();   // ONE barrier/chunk: gate visible + GEMM1 reads done
            int t_chunk = t0 + (r0 - 64);
            if (USEG && r0 >= 64 && t_chunk >= 4096) {
                // gate tile -> G in fragment order (16B/thread, coalesced)
                int tt = ((tid & 256) >> 4) + (tid & 15);
                int cc = ((tid >> 6) & 3) * 32 + ((tid >> 4) & 3) * 8;
                bf16x8 gv = *(const bf16x8*)(s2 + tt * PL + cc);
                *(bf16x8*)(Gl + ((size_t)n * 4096 + (t_chunk - 4096)) * 128 + tid * 8) = gv;
            }
            // res GEMM + residual add -> bout chunk
            f32x4 acc2[2] = {z,z};
            #pragma unroll
            for (int kb = 0; kb < 4; ++kb) {
                int koff = kb * 32 + q * 8;
                #pragma unroll
                for (int nt = 0; nt < 2; ++nt) {
                    bf16x8 bf = *(const bf16x8*)(s2 + (nt * 16 + i16) * PL + koff);
                    acc2[nt] = mfma16(ar[kb], bf, acc2[nt]);
                }
            }
            #pragma unroll
            for (int nt = 0; nt < 2; ++nt) {
                int rr = r0 + nt * 16 + i16;
                bf16x4 lv = *(const bf16x4*)(bin + rr * PL + c_base);
                bf16x4 o4;
                #pragma unroll
                for (int j = 0; j < 4; ++j)
                    o4[j] = (bf16_t)((float)lv[j] + acc2[nt][j]);
                *(bf16x4*)(bout + rr * PL + c_base) = o4;
            }
            p ^= 1;   // next chunk uses other sm2; this one safe after next barrier
        }
        barrier_nodrain();   // layer-end: all bout writes visible before swap
        bf16_t* tsw = bin; bin = bout; bout = tsw;
    }
    // final: rows [64,192) of bin -> l_out [t0, t0+128)
    {
        int rr0 = tid >> 4, col = (tid & 15) * 8;
        for (int rr = 64 + rr0; rr < 192; rr += 32) {
            *(i32x4*)(l_out + (base + t0 - 64 + rr) * 128 + col) =
                *(const i32x4*)(bin + rr * PL + col);
        }
    }
}

// ---------------- single layer, TT=32 (r3-proven; used for dil>=64) ----------------
template<int USEG>
__global__ __launch_bounds__(512, 4) void k_layer(
    const bf16_t* __restrict__ l_in, bf16_t* __restrict__ l_out,
    float* __restrict__ sbuf, bf16_t* __restrict__ Gl,
    const bf16_t* __restrict__ Ad, const bf16_t* __restrict__ Ar,
    const bf16_t* __restrict__ Ak, const float* __restrict__ condL,
    int dil, int t_base, int do_res)
{
    __shared__ __align__(16) bf16_t smA[64 * PL];   // staging (cur|del or combined)
    __shared__ __align__(16) bf16_t sm2[32 * PL];   // gate
    int tid = threadIdx.x;
    int n = blockIdx.y, t0 = t_base + blockIdx.x * 32;
    int lane = tid & 63, w = tid >> 6, i16 = lane & 15, q = lane >> 4;
    f32x4 z = {0.f,0.f,0.f,0.f};
    const float* cond = condL + (size_t)n * 4096;
    int r = tid >> 4, col = (tid & 15) * 8;
    int c_base = w * 16 + q * 4;
    size_t base = (size_t)n * 8192;

    float cv_s[4], cv_t[4];
    #pragma unroll
    for (int j = 0; j < 4; ++j) {
        cv_s[j] = cond[(c_base + j) * 16 + i16];
        cv_t[j] = cond[(c_base + j + 128) * 16 + i16];
    }
    const bf16x8* AdF = (const bf16x8*)Ad;
    bf16x8 a_s[8], a_t[8];
    #pragma unroll
    for (int kb = 0; kb < 8; ++kb) {
        a_s[kb] = AdF[((size_t)w * 8 + kb) * 64 + lane];
        a_t[kb] = AdF[((size_t)(w + 8) * 8 + kb) * 64 + lane];
    }

    const bf16_t* curp;
    const bf16_t* delp;
    if (dil < 32) {
        int cnt = (32 + dil) * 16;
        for (int idx = tid; idx < cnt; idx += 512) {
            int rr = idx >> 4, c2 = (idx & 15) * 8;
            *(i32x4*)(smA + rr * PL + c2) =
                *(const i32x4*)(l_in + (base + t0 - dil + rr) * 128 + c2);
        }
        delp = smA; curp = smA + dil * PL;
    } else {
        *(i32x4*)(smA + r * PL + col) =
            *(const i32x4*)(l_in + (base + t0 + r) * 128 + col);
        int gp = t0 - dil + r;
        i32x4 v = {0, 0, 0, 0};
        if (gp >= 0) v = *(const i32x4*)(l_in + (base + gp) * 128 + col);
        *(i32x4*)(smA + (32 + r) * PL + col) = v;
        curp = smA; delp = smA + 32 * PL;
    }
    barrier_nodrain();

    f32x4 accs[2] = {z,z}, acct[2] = {z,z};
    #pragma unroll
    for (int kb = 0; kb < 8; ++kb) {
        const bf16_t* bsrc = (kb < 4) ? delp : curp;
        int koff = (kb & 3) * 32 + q * 8;
        bf16x8 bf[2];
        #pragma unroll
        for (int nt = 0; nt < 2; ++nt)
            bf[nt] = *(const bf16x8*)(bsrc + (nt * 16 + i16) * PL + koff);
        #pragma unroll
        for (int nt = 0; nt < 2; ++nt) {
            accs[nt] = mfma16(a_s[kb], bf[nt], accs[nt]);
            acct[nt] = mfma16(a_t[kb], bf[nt], acct[nt]);
        }
    }

    const bf16x8* ArF = (const bf16x8*)Ar;
    bf16x8 ar[4];
    if (do_res) {
        #pragma unroll
        for (int kb = 0; kb < 4; ++kb)
            ar[kb] = ArF[((size_t)w * 4 + kb) * 64 + lane];
    }

    {
        #pragma unroll
        for (int nt = 0; nt < 2; ++nt) {
            bf16x4 g4;
            #pragma unroll
            for (int j = 0; j < 4; ++j)
                g4[j] = (bf16_t)gatef(accs[nt][j] + cv_s[j], acct[nt][j] + cv_t[j]);
            *(bf16x4*)(sm2 + (nt * 16 + i16) * PL + c_base) = g4;
        }
    }
    barrier_nodrain();

    if (USEG) {
        if (t0 >= 4096) {
            int tt = ((tid & 256) >> 4) + (tid & 15);
            int cc = ((tid >> 6) & 3) * 32 + ((tid >> 4) & 3) * 8;
            bf16x8 gv = *(const bf16x8*)(sm2 + tt * PL + cc);
            *(bf16x8*)(Gl + ((size_t)n * 4096 + (t0 - 4096)) * 128 + tid * 8) = gv;
        }
    }

    f32x4 acc2[2] = {z,z};
    if (do_res || !USEG) {
        int do_skip = (!USEG) && (t0 >= 4096);
        f32x4 acc3[2][2] = {{z,z},{z,z}};
        const bf16x8* AkF = (const bf16x8*)Ak;
        #pragma unroll
        for (int kb = 0; kb < 4; ++kb) {
            int koff = kb * 32 + q * 8;
            bf16x8 bf[2];
            #pragma unroll
            for (int nt = 0; nt < 2; ++nt)
                bf[nt] = *(const bf16x8*)(sm2 + (nt * 16 + i16) * PL + koff);
            if (do_res) {
                #pragma unroll
                for (int nt = 0; nt < 2; ++nt) acc2[nt] = mfma16(ar[kb], bf[nt], acc2[nt]);
            }
            if (do_skip) {
                #pragma unroll
                for (int mt2 = 0; mt2 < 2; ++mt2) {
                    bf16x8 ak = AkF[((size_t)(2 * w + mt2) * 4 + kb) * 64 + lane];
                    #pragma unroll
                    for (int nt = 0; nt < 2; ++nt)
                        acc3[mt2][nt] = mfma16(ak, bf[nt], acc3[mt2][nt]);
                }
            }
        }
        if (do_skip) {
            float* sp = sbuf + (size_t)n * 256 * 4096 + (t0 - 4096);
            #pragma unroll
            for (int mt2 = 0; mt2 < 2; ++mt2)
                #pragma unroll
                for (int nt = 0; nt < 2; ++nt)
                    #pragma unroll
                    for (int j = 0; j < 4; ++j) {
                        int o = (2 * w + mt2) * 16 + q * 4 + j;
                        sp[(size_t)o * 4096 + nt * 16 + i16] += acc3[mt2][nt][j];
                    }
        }
    }

    if (do_res) {
        #pragma unroll
        for (int nt = 0; nt < 2; ++nt) {
            int trow = (nt * 16 + i16) * PL;
            bf16x4 lv = *(const bf16x4*)(curp + trow + c_base);
            bf16x4 o4;
            #pragma unroll
            for (int j = 0; j < 4; ++j)
                o4[j] = (bf16_t)((float)lv[j] + acc2[nt][j]);
            *(bf16x4*)(l_out + (base + t0 + nt * 16 + i16) * 128 + c_base) = o4;
        }
    }
}

// ---------------- deferred skip mega-GEMM: s += sum_i skip_i @ g_i ----------------
#define SKIP_HALF(I, AKU, AKP, GW0, GW1)                                        \
    {                                                                           \
        const int i_ = (I);                                                     \
        if (i_ + 1 < 30) {                                                      \
            bf16_t* db = gbuf[(i_ + 1) & 1];                                    \
            *(i32x4*)(db + tid * 8) = GW0;                                      \
            *(i32x4*)(db + 4096 + tid * 8) = GW1;                               \
        }                                                                       \
        if (i_ + 3 < 30) {                                                      \
            const bf16_t* srcp = gb + (size_t)(i_ + 3) * GLS;                   \
            GW0 = *(const i32x4*)(srcp);                                        \
            GW1 = *(const i32x4*)(srcp + 4096);                                 \
        }                                                                       \
        if (i_ + 1 < 30) {                                                      \
            const bf16x8* An = (const bf16x8*)(Askp + (size_t)(i_ + 1) * 32768);\
            _Pragma("unroll")                                                   \
            for (int kb = 0; kb < 4; ++kb) {                                    \
                AKP[2 * kb]     = An[fi0 + kb * 64];                            \
                AKP[2 * kb + 1] = An[fi1 + kb * 64];                            \
            }                                                                   \
        }                                                                       \
        const bf16_t* gp_ = gbuf[i_ & 1];                                       \
        _Pragma("unroll")                                                       \
        for (int kb = 0; kb < 4; ++kb) {                                        \
            _Pragma("unroll")                                                   \
            for (int nt = 0; nt < 4; ++nt) {                                    \
                bf16x8 bfv = *(const bf16x8*)(gp_ + (nt >> 1) * 4096 +          \
                              (((nt & 1) * 4 + kb) * 64 + lane) * 8);           \
                acc[0][nt] = mfma16(AKU[2 * kb], bfv, acc[0][nt]);              \
                acc[1][nt] = mfma16(AKU[2 * kb + 1], bfv, acc[1][nt]);          \
            }                                                                   \
        }                                                                       \
        if (i_ + 1 < 30) {                                                      \
            asm volatile("s_waitcnt lgkmcnt(0)" ::: "memory");                  \
            __builtin_amdgcn_sched_barrier(0);                                  \
            __builtin_amdgcn_s_barrier();                                       \
            __builtin_amdgcn_sched_barrier(0);                                  \
        }                                                                       \
    }

__global__ __launch_bounds__(512, 2) void k_skip(
    const bf16_t* __restrict__ G, float* __restrict__ sbuf,
    const bf16_t* __restrict__ Askp)
{
    __shared__ __align__(16) bf16_t gbuf[2][8192];
    int tid = threadIdx.x;
    int n = blockIdx.y, t0 = blockIdx.x * 64;
    int lane = tid & 63, w = tid >> 6, i16 = lane & 15, q = lane >> 4;
    f32x4 z = {0.f,0.f,0.f,0.f};
    f32x4 acc[2][4] = {{z,z,z,z},{z,z,z,z}};
    const size_t GLS = (size_t)4 * 4096 * 128;   // per-layer stride in G (elems)
    const bf16_t* gb = G + ((size_t)n * 4096 + t0) * 128 + tid * 8;
    int fi0 = (2 * w) * 256 + lane;
    int fi1 = fi0 + 256;
    bf16x8 akA[8], akB[8];
    {
        const bf16x8* A0 = (const bf16x8*)Askp;
        #pragma unroll
        for (int kb = 0; kb < 4; ++kb) {
            akA[2 * kb]     = A0[fi0 + kb * 64];
            akA[2 * kb + 1] = A0[fi1 + kb * 64];
        }
    }
    i32x4 gA0, gA1, gB0, gB1;
    {
        i32x4 t0v = *(const i32x4*)(gb);
        i32x4 t1v = *(const i32x4*)(gb + 4096);
        *(i32x4*)(gbuf[0] + tid * 8) = t0v;
        *(i32x4*)(gbuf[0] + 4096 + tid * 8) = t1v;
    }
    gA0 = *(const i32x4*)(gb + 1 * GLS);
    gA1 = *(const i32x4*)(gb + 1 * GLS + 4096);
    gB0 = *(const i32x4*)(gb + 2 * GLS);
    gB1 = *(const i32x4*)(gb + 2 * GLS + 4096);
    __syncthreads();   // prologue: single full drain
    #pragma unroll 1
    for (int ii = 0; ii < 30; ii += 2) {
        SKIP_HALF(ii,     akA, akB, gA0, gA1)
        SKIP_HALF(ii + 1, akB, akA, gB0, gB1)
    }
    float* sp = sbuf + (size_t)n * 256 * 4096 + t0;
    #pragma unroll
    for (int mt2 = 0; mt2 < 2; ++mt2)
        #pragma unroll
        for (int nt = 0; nt < 4; ++nt)
            #pragma unroll
            for (int j = 0; j < 4; ++j) {
                int o = (2 * w + mt2) * 16 + q * 4 + j;
                sp[(size_t)o * 4096 + nt * 16 + i16] += acc[mt2][nt][j];
            }
}

// ---------------- end: out = relu(end1@relu(s) + b1 + cond2_tiled) ----------------
__global__ __launch_bounds__(512) void k_end(
    const float* __restrict__ sbuf, float* __restrict__ out,
    const bf16_t* __restrict__ Ae, const float* __restrict__ cond2,
    const float* __restrict__ b1)
{
    __shared__ __align__(16) bf16_t st[64 * PX];
    __shared__ float c2[4096];
    __shared__ float b1s[256];
    int tid = threadIdx.x;
    int n = blockIdx.y, t0 = blockIdx.x * 64;
    int lane = tid & 63, w = tid >> 6, i16 = lane & 15, q = lane >> 4;
    f32x4 z = {0.f,0.f,0.f,0.f};
    {
        int t = tid & 63;
        for (int c = tid >> 6; c < 256; c += 8) {
            float v = sbuf[((size_t)n * 256 + c) * 4096 + t0 + t];
            st[t * PX + c] = (bf16_t)fmaxf(v, 0.f);
        }
        const f32x4* cc = (const f32x4*)(cond2 + (size_t)n * 4096);
        for (int idx = tid; idx < 1024; idx += 512) ((f32x4*)c2)[idx] = cc[idx];
        if (tid < 64) ((f32x4*)b1s)[tid] = ((const f32x4*)b1)[tid];
    }
    __syncthreads();
    f32x4 acc[2][4] = {{z,z,z,z},{z,z,z,z}};
    #pragma unroll
    for (int kb = 0; kb < 8; ++kb) {
        int koff = kb * 32 + q * 8;
        bf16x8 bf[4];
        #pragma unroll
        for (int nt = 0; nt < 4; ++nt)
            bf[nt] = *(const bf16x8*)(st + (nt * 16 + i16) * PX + koff);
        #pragma unroll
        for (int mt2 = 0; mt2 < 2; ++mt2) {
            bf16x8 af = *(const bf16x8*)(Ae + ((((size_t)2 * w + mt2) * 8 + kb) * 64 + lane) * 8);
            #pragma unroll
            for (int nt = 0; nt < 4; ++nt) acc[mt2][nt] = mfma16(af, bf[nt], acc[mt2][nt]);
        }
    }
    #pragma unroll
    for (int mt2 = 0; mt2 < 2; ++mt2)
        #pragma unroll
        for (int j = 0; j < 4; ++j) {
            int o = (2 * w + mt2) * 16 + q * 4 + j;
            float bb = b1s[o] + c2[o * 16 + i16];
            #pragma unroll
            for (int nt = 0; nt < 4; ++nt) {
                float v = acc[mt2][nt][j] + bb;
                out[((size_t)n * 256 + o) * 4096 + t0 + nt * 16 + i16] = fmaxf(v, 0.f);
            }
        }
}

extern "C" void kernel_launch(void* const* d_in, const int* in_sizes, int n_in,
                              void* d_out, int out_size, void* d_ws, size_t ws_size,
                              hipStream_t stream) {
    const float* x   = (const float*)d_in[0];
    const float* en  = (const float*)d_in[1];
    const float* s1w = (const float*)d_in[2];
    const float* s2w = (const float*)d_in[3];
    const float* cw  = (const float*)d_in[4];
    const float* dw  = (const float*)d_in[5];
    const float* rw  = (const float*)d_in[6];
    const float* kw  = (const float*)d_in[7];
    const float* e1w = (const float*)d_in[8];
    const float* e1b = (const float*)d_in[9];
    const float* e2w = (const float*)d_in[10];
    const float* e2b = (const float*)d_in[11];
    float* out = (float*)d_out;

    char* p = (char*)d_ws;
    auto take = [&](size_t bytes) {
        char* r = p;
        p += (bytes + 255) & ~(size_t)255;
        return r;
    };
    bf16_t* A1   = (bf16_t*)take((size_t)128 * 256 * 2);
    bf16_t* A2   = (bf16_t*)take((size_t)256 * 128 * 2);
    bf16_t* Ae   = (bf16_t*)take((size_t)256 * 256 * 2);
    bf16_t* Adil = (bf16_t*)take((size_t)30 * 65536 * 2);
    bf16_t* Ares = (bf16_t*)take((size_t)30 * 16384 * 2);
    bf16_t* Askp = (bf16_t*)take((size_t)30 * 32768 * 2);
    float*  condA= (float*)take((size_t)30 * 16384 * 4);
    float*  cond2= (float*)take((size_t)16384 * 4);
    bf16_t* la   = (bf16_t*)take((size_t)4 * 8192 * 128 * 2);
    bf16_t* lb   = (bf16_t*)take((size_t)4 * 8192 * 128 * 2);
    float*  sbuf = (float*)take((size_t)4 * 256 * 4096 * 4);
    bf16_t* G    = (bf16_t*)take((size_t)30 * 4 * 4096 * 128 * 2);  // last
    bool useG = ((size_t)(p - (char*)d_ws) <= ws_size);

    k_prep<<<2240, 256, 0, stream>>>(rw, kw, s1w, s2w, e1w, dw,
                                     cw, e2w, e2b, en,
                                     Ares, Askp, A1, A2, Ae, Adil, condA, cond2);

    // causal trim table (host)
    int a[30];
    a[29] = 4096;
    for (int i = 28; i >= 0; --i) {
        int nx = a[i + 1] - (1 << ((i + 1) % 10));
        a[i] = nx < 4096 ? (nx & ~63) : 4096;
    }

    k_start<<<dim3(127, 4), 512, 0, stream>>>(x, la, sbuf, A1, A2, 64);

    bf16_t* src = la;
    bf16_t* dst = lb;
    if (useG) {
        for (int g = 0; g < 3; ++g) {
            int g0 = g * 10;
            int aG = a[g0] & ~127;
            dim3 gridF((8192 - aG) / 128, 4);
            k_fuse<1><<<gridF, 512, 0, stream>>>(src, dst, G, Adil, Ares,
                                                 condA, aG, g0);
            { bf16_t* t = src; src = dst; dst = t; }
            for (int i = g0 + 6; i < g0 + 10; ++i) {
                dim3 grid2((8192 - a[i]) / 32, 4);
                k_layer<1><<<grid2, 512, 0, stream>>>(src, dst, sbuf,
                    G + (size_t)i * 4 * 4096 * 128,
                    Adil + (size_t)i * 65536, Ares + (size_t)i * 16384,
                    Askp + (size_t)i * 32768, condA + (size_t)i * 16384,
                    1 << (i % 10), a[i], i < 29 ? 1 : 0);
                bf16_t* t = src; src = dst; dst = t;
            }
        }
        k_skip<<<dim3(64, 4), 512, 0, stream>>>(G, sbuf, Askp);
    } else {
        for (int i = 0; i < 30; ++i) {
            dim3 grid((8192 - a[i]) / 32, 4);
            k_layer<0><<<grid, 512, 0, stream>>>(src, dst, sbuf, (bf16_t*)nullptr,
                Adil + (size_t)i * 65536, Ares + (size_t)i * 16384,
                Askp + (size_t)i * 32768, condA + (size_t)i * 16384,
                1 << (i % 10), a[i], i < 29 ? 1 : 0);
            bf16_t* t = src; src = dst; dst = t;
        }
    }
    k_end<<<dim3(64, 4), 512, 0, stream>>>(sbuf, out, Ae, cond2, e1b);
}